// Round 6
// baseline (123.371 us; speedup 1.0000x reference)
//
#include <hip/hip_runtime.h>
#include <hip/hip_bf16.h>

#define B_ 4
#define C_ 64
#define N_ 4096
#define EPS_ 1e-5f
// p = exp(s*0.125) = exp2(s * 0.125*log2e); folded into Q at qkv-write time
#define C2_ 0.18033688011112042f

typedef __hip_bfloat16 bf16;
typedef __attribute__((ext_vector_type(8))) short short8;
typedef __attribute__((ext_vector_type(4))) short short4v;
typedef __attribute__((ext_vector_type(4))) float f32x4;

__device__ __forceinline__ float b2f(bf16 v) { return __bfloat162float(v); }

__device__ __forceinline__ short f2bs(float f) {
  union { bf16 h; short s; } u;
  u.h = __float2bfloat16(f);
  return u.s;
}

__device__ __forceinline__ short8 pk8(const float* f) {
  union { short8 v; short s[8]; } u;
#pragma unroll
  for (int i = 0; i < 8; ++i) u.s[i] = f2bs(f[i]);
  return u.v;
}

__device__ __forceinline__ void up8(short8 v, float* d) {
  union { short8 v; unsigned u[4]; } x;
  x.v = v;
  d[0] = __uint_as_float(x.u[0] << 16);
  d[1] = __uint_as_float(x.u[0] & 0xffff0000u);
  d[2] = __uint_as_float(x.u[1] << 16);
  d[3] = __uint_as_float(x.u[1] & 0xffff0000u);
  d[4] = __uint_as_float(x.u[2] << 16);
  d[5] = __uint_as_float(x.u[2] & 0xffff0000u);
  d[6] = __uint_as_float(x.u[3] << 16);
  d[7] = __uint_as_float(x.u[3] & 0xffff0000u);
}

template <bool F32>
__device__ __forceinline__ float ldx(const void* p, size_t idx) {
  if (F32) return ((const float*)p)[idx];
  return b2f(((const bf16*)p)[idx]);
}

template <bool F32>
__device__ __forceinline__ short8 ld8(const void* p, int idx) {
  if (F32) {
    const float* fp = (const float*)p + idx;
    float tmp[8];
    *(float4*)&tmp[0] = *(const float4*)fp;
    *(float4*)&tmp[4] = *(const float4*)(fp + 4);
    return pk8(tmp);
  }
  return *(const short8*)((const bf16*)p + idx);
}

__device__ __forceinline__ f32x4 mfma32(short8 a, short8 b, f32x4 c) {
  return __builtin_amdgcn_mfma_f32_16x16x32_bf16(a, b, c, 0, 0, 0);
}
__device__ __forceinline__ f32x4 mfma16(short4v a, short4v b, f32x4 c) {
  return __builtin_amdgcn_mfma_f32_16x16x16bf16_1k(a, b, c, 0, 0, 0);
}

// Layouts (bf16 element offsets):
// Q  B-frag(K=32): ((b*256+tg)*2+ks)*512 + lane*8 + jj   (k=c, n=token)
// K  A-frag(K=32): ((b*64+kt)*8+jb*2+ks)*512 + lane*8+jj (m=token, k=c)
// V^T A-frag(K=16): ((b*64+kt)*16+cb*4+jb)*256 + lane*4+jj (m=c, k=token)

// ---------------- Kernel 1: stats + integrated dtype probe ------------------
template <bool F32>
__device__ __forceinline__ void stats_sum(const void* x, int bc, int t,
                                          float& s, float& s2) {
  if (F32) {
    const float4* xp = (const float4*)((const float*)x + (size_t)bc * N_);
#pragma unroll
    for (int r = 0; r < 4; ++r) {
      const float4 v = xp[r * 256 + t];
      s += (v.x + v.y) + (v.z + v.w);
      s2 += (v.x * v.x + v.y * v.y) + (v.z * v.z + v.w * v.w);
    }
  } else {
    const bf16* xp = (const bf16*)x + (size_t)bc * N_;
#pragma unroll
    for (int r = 0; r < 2; ++r) {
      float f[8];
      up8(*(const short8*)(xp + (r * 256 + t) * 8), f);
#pragma unroll
      for (int i = 0; i < 8; ++i) { s += f[i]; s2 += f[i] * f[i]; }
    }
  }
}

__global__ __launch_bounds__(256) void k_stats(const void* __restrict__ x,
                                               float* __restrict__ meanArr,
                                               float* __restrict__ rstdArr,
                                               int* __restrict__ flag) {
  const int bc = blockIdx.x, t = threadIdx.x;
  __shared__ float ps[4], ps2[4];
  __shared__ int pflag;
  {
    const ushort* xw = (const ushort*)x + (size_t)bc * 4096;
    int cnt = 0;
#pragma unroll
    for (int j = 0; j < 4; ++j) {
      const ushort4 u = *(const ushort4*)(xw + t * 16 + j * 4);
      cnt += ((u.x >> 7) & 0xFF) >= 143;
      cnt += ((u.y >> 7) & 0xFF) >= 143;
      cnt += ((u.z >> 7) & 0xFF) >= 143;
      cnt += ((u.w >> 7) & 0xFF) >= 143;
    }
#pragma unroll
    for (int off = 32; off > 0; off >>= 1) cnt += __shfl_down(cnt, off, 64);
    if (t == 0) pflag = 0;
    __syncthreads();
    if ((t & 63) == 0 && cnt > 16) atomicAdd(&pflag, cnt);
    __syncthreads();
  }
  const bool f32 = pflag > 64;
  float s = 0.f, s2 = 0.f;
  if (f32) stats_sum<true>(x, bc, t, s, s2);
  else stats_sum<false>(x, bc, t, s, s2);
#pragma unroll
  for (int off = 32; off > 0; off >>= 1) {
    s += __shfl_down(s, off, 64);
    s2 += __shfl_down(s2, off, 64);
  }
  if ((t & 63) == 0) { ps[t >> 6] = s; ps2[t >> 6] = s2; }
  __syncthreads();
  if (t == 0) {
    const float S = (ps[0] + ps[1]) + (ps[2] + ps[3]);
    const float S2 = (ps2[0] + ps2[1]) + (ps2[2] + ps2[3]);
    const float mean = S * (1.0f / N_);
    const float var = S2 * (1.0f / N_) - mean * mean;
    meanArr[bc] = mean;
    rstdArr[bc] = rsqrtf(var + EPS_);
    flag[0] = f32 ? 1 : 0;
  }
}

// ---------------- Kernel 2: norm + qkv projection (MFMA) --------------------
// Q is pre-scaled by C2_ = 0.125*log2(e) so attention uses exp2(sv) directly.
template <bool F32>
__device__ __forceinline__ void qkv_body(const void* x, const void* wqkv,
                                         const void* bqkv, const float* meanArr,
                                         const float* rstdArr, bf16* q, bf16* k,
                                         bf16* v, short* HB) {
  const int t = threadIdx.x, tj = blockIdx.x, b = blockIdx.y;
  const int n0 = tj * 64;
  {
    const int li = t & 15, nbt = (t >> 4) & 3, cg = t >> 6;
    const int n = n0 + nbt * 16 + li;
    const float* mb_ = meanArr + b * 64;
    const float* rb_ = rstdArr + b * 64;
    float hv[16];
#pragma unroll
    for (int i = 0; i < 16; ++i) {
      const int c = cg * 16 + i;
      hv[i] = (ldx<F32>(x, ((size_t)(b * 64 + c)) * N_ + n) - mb_[c]) * rb_[c];
    }
#pragma unroll
    for (int c8 = 0; c8 < 2; ++c8) {
      const int ks = cg >> 1, qd = (cg & 1) * 2 + c8;
      *(short8*)&HB[((nbt * 2 + ks) * 64 + qd * 16 + li) * 8] = pk8(&hv[c8 * 8]);
    }
  }
  __syncthreads();
  const int l = t & 63, w = t >> 6, li = l & 15, quad = l >> 4;
  short8 Wf[3][2];
#pragma unroll
  for (int sec = 0; sec < 3; ++sec)
#pragma unroll
    for (int ks = 0; ks < 2; ++ks)
      Wf[sec][ks] = ld8<F32>(wqkv, (sec * 64 + w * 16 + li) * 64 + ks * 32 + quad * 8);
  short8 Hf[4][2];
#pragma unroll
  for (int nb = 0; nb < 4; ++nb)
#pragma unroll
    for (int ks = 0; ks < 2; ++ks)
      Hf[nb][ks] = *(const short8*)&HB[((nb * 2 + ks) * 64 + l) * 8];
  float bq[4], bk[4];
#pragma unroll
  for (int r = 0; r < 4; ++r) {
    bq[r] = ldx<F32>(bqkv, w * 16 + quad * 4 + r);
    bk[r] = ldx<F32>(bqkv, 64 + w * 16 + quad * 4 + r);
  }
  const float bv = ldx<F32>(bqkv, 128 + w * 16 + li);
  const int lhi = ((w & 1) * 2 + (quad >> 1)) * 16 + li;
  const int jj0 = (quad & 1) * 4;
#pragma unroll
  for (int nb = 0; nb < 4; ++nb) {
    f32x4 dq = {0.f, 0.f, 0.f, 0.f}, dk = dq, dv = dq;
    dq = mfma32(Wf[0][0], Hf[nb][0], dq);
    dq = mfma32(Wf[0][1], Hf[nb][1], dq);
    dk = mfma32(Wf[1][0], Hf[nb][0], dk);
    dk = mfma32(Wf[1][1], Hf[nb][1], dk);
    dv = mfma32(Hf[nb][0], Wf[2][0], dv);
    dv = mfma32(Hf[nb][1], Wf[2][1], dv);
    union { ushort4 u; short s[4]; } pq, pk_, pv;
#pragma unroll
    for (int r = 0; r < 4; ++r) {
      pq.s[r] = f2bs((dq[r] + bq[r]) * C2_);
      pk_.s[r] = f2bs(dk[r] + bk[r]);
      pv.s[r] = f2bs(dv[r] + bv);
    }
    *(ushort4*)&q[(((size_t)(b * 256 + tj * 4 + nb)) * 2 + (w >> 1)) * 512 + lhi * 8 + jj0] = pq.u;
    *(ushort4*)&k[(((size_t)(b * 64 + tj)) * 8 + nb * 2 + (w >> 1)) * 512 + lhi * 8 + jj0] = pk_.u;
    *(ushort4*)&v[(((size_t)(b * 64 + tj)) * 16 + w * 4 + nb) * 256 + (quad * 16 + li) * 4] = pv.u;
  }
}
__global__ __launch_bounds__(256) void k_qkv(
    const void* __restrict__ x, const void* __restrict__ wqkv,
    const void* __restrict__ bqkv, const float* __restrict__ meanArr,
    const float* __restrict__ rstdArr, bf16* __restrict__ q,
    bf16* __restrict__ k, bf16* __restrict__ v, const int* __restrict__ flag) {
  __shared__ short HB[4096];
  if (*flag) qkv_body<true>(x, wqkv, bqkv, meanArr, rstdArr, q, k, v, HB);
  else qkv_body<false>(x, wqkv, bqkv, meanArr, rstdArr, q, k, v, HB);
}

// ---------------- Kernel 3: attention over ALL keys + proj + residual -------
// grid 512 = (b, qt): each block owns 32 queries, iterates all 64 K/V tiles.
// 3-deep LDS pipeline with COUNTED vmcnt (never 0 in the loop) + raw
// s_barrier: stages for tiles it+1, it+2 stay in flight across the barrier,
// so the per-iteration drain stall of __syncthreads (vmcnt(0)) is gone.
// Protocol per iter: vmcnt(4) [own buf-it loads done; retires in order] ->
// s_barrier [all waves' buf-it done; V chunks are cross-wave] ->
// sched_barrier(0) [no LDS read hoists above] -> stage(it+2) -> compute.
__device__ __forceinline__ void stage(short* dst, const bf16* ks_,
                                      const bf16* vs_, int w, int ln) {
#pragma unroll
  for (int i = 0; i < 2; ++i) {
    const int off = w * 1024 + i * 512;
    __builtin_amdgcn_global_load_lds(
        (const __attribute__((address_space(1))) unsigned int*)(ks_ + off + ln * 8),
        (__attribute__((address_space(3))) unsigned int*)(dst + off), 16, 0, 0);
    __builtin_amdgcn_global_load_lds(
        (const __attribute__((address_space(1))) unsigned int*)(vs_ + off + ln * 8),
        (__attribute__((address_space(3))) unsigned int*)(dst + 4096 + off), 16, 0, 0);
  }
}

template <bool F32>
__device__ __forceinline__ void attnproj_body(
    const bf16* __restrict__ qg, const bf16* __restrict__ kg,
    const bf16* __restrict__ vg, const void* __restrict__ xg,
    const void* __restrict__ wp, const void* __restrict__ bp,
    void* __restrict__ outv, short (*KV)[8192], float* LSm, int b, int qt) {
  const int t = threadIdx.x, l = t & 63, w = t >> 6, li = l & 15, quad = l >> 4;

  short8 Qf[2][2];
#pragma unroll
  for (int q = 0; q < 2; ++q)
#pragma unroll
    for (int ks = 0; ks < 2; ++ks)
      Qf[q][ks] = *(const short8*)(qg +
          (((size_t)(b * 256 + qt * 2 + q)) * 2 + ks) * 512 + l * 8);

  f32x4 O[4][2];  // [cb][q]; C-layout: c = cb*16+quad*4+r, n-col = li
#pragma unroll
  for (int cb = 0; cb < 4; ++cb)
#pragma unroll
    for (int q = 0; q < 2; ++q) O[cb][q] = {0.f, 0.f, 0.f, 0.f};
  float ls[2] = {0.f, 0.f};

  const bf16* kbase = kg + ((size_t)(b * 64)) * 4096;
  const bf16* vbase = vg + ((size_t)(b * 64)) * 4096;

  // prologue: 2 tiles in flight
  stage(&KV[0][0], kbase, vbase, w, l);
  stage(&KV[1][0], kbase + 4096, vbase + 4096, w, l);
  int cur = 0;
  for (int it = 0; it < 64; ++it) {
    if (it < 63)
      asm volatile("s_waitcnt vmcnt(4)" ::: "memory");
    else
      asm volatile("s_waitcnt vmcnt(0)" ::: "memory");
    __builtin_amdgcn_s_barrier();
    __builtin_amdgcn_sched_barrier(0);
    if (it + 2 < 64) {
      int nx2 = cur + 2;
      if (nx2 >= 3) nx2 -= 3;
      stage(&KV[nx2][0], kbase + (size_t)(it + 2) * 4096,
            vbase + (size_t)(it + 2) * 4096, w, l);
    }
    const short* buf = &KV[cur][0];
    short8 Kf[2];
#pragma unroll
    for (int ks = 0; ks < 2; ++ks)
      Kf[ks] = *(const short8*)&buf[(w * 2 + ks) * 512 + l * 8];
    short4v Vf[4];
#pragma unroll
    for (int cb = 0; cb < 4; ++cb)
      Vf[cb] = *(const short4v*)&buf[4096 + (cb * 4 + w) * 256 + l * 4];
#pragma unroll
    for (int q = 0; q < 2; ++q) {
      f32x4 sv = {0.f, 0.f, 0.f, 0.f};
      sv = mfma32(Kf[0], Qf[q][0], sv);
      sv = mfma32(Kf[1], Qf[q][1], sv);
      const float p0 = exp2f(sv[0]), p1 = exp2f(sv[1]);
      const float p2 = exp2f(sv[2]), p3 = exp2f(sv[3]);
      ls[q] += (p0 + p1) + (p2 + p3);
      union { short4v v; __hip_bfloat162 h[2]; } pu;
      pu.h[0] = __float22bfloat162_rn(make_float2(p0, p1));
      pu.h[1] = __float22bfloat162_rn(make_float2(p2, p3));
#pragma unroll
      for (int cb = 0; cb < 4; ++cb)
        O[cb][q] = mfma16(Vf[cb], pu.v, O[cb][q]);
    }
    cur = (cur + 1 == 3) ? 0 : cur + 1;
  }
  __syncthreads();  // align all waves before LDS buffers are reused below
  // intra-wave: sum denominator across quads (keys quad-partitioned)
#pragma unroll
  for (int q = 0; q < 2; ++q) {
    ls[q] += __shfl_xor(ls[q], 16, 64);
    ls[q] += __shfl_xor(ls[q], 32, 64);
  }
  // 4-way O / ls merge across waves via LDS (tree: 1,3 -> 0,2 -> 0)
  float* PA = (float*)&KV[0][0];  // [q][c][li] f32, 8 KB
  float* PB = (float*)&KV[1][0];
  if (w == 1 || w == 3) {
    float* P = (w == 1) ? PA : PB;
#pragma unroll
    for (int q = 0; q < 2; ++q) {
#pragma unroll
      for (int cb = 0; cb < 4; ++cb)
#pragma unroll
        for (int r = 0; r < 4; ++r)
          P[q * 1024 + (cb * 16 + quad * 4 + r) * 16 + li] = O[cb][q][r];
      if (l < 16) LSm[((w >> 1) * 2 + q) * 16 + l] = ls[q];
    }
  }
  __syncthreads();
  if (w == 0 || w == 2) {
    const float* P = (w == 0) ? PA : PB;
    const int si = w >> 1;
#pragma unroll
    for (int q = 0; q < 2; ++q) {
#pragma unroll
      for (int cb = 0; cb < 4; ++cb)
#pragma unroll
        for (int r = 0; r < 4; ++r)
          O[cb][q][r] += P[q * 1024 + (cb * 16 + quad * 4 + r) * 16 + li];
      ls[q] += LSm[(si * 2 + q) * 16 + li];
    }
  }
  __syncthreads();
  if (w == 2) {
#pragma unroll
    for (int q = 0; q < 2; ++q) {
#pragma unroll
      for (int cb = 0; cb < 4; ++cb)
#pragma unroll
        for (int r = 0; r < 4; ++r)
          PA[q * 1024 + (cb * 16 + quad * 4 + r) * 16 + li] = O[cb][q][r];
      if (l < 16) LSm[(2 * 2 + q) * 16 + l] = ls[q];
    }
  }
  __syncthreads();
  bf16* HT = (bf16*)&KV[1][0];  // h' tile [32 n][72 c] bf16 (72 = pad)
  if (w == 0) {
#pragma unroll
    for (int q = 0; q < 2; ++q) {
#pragma unroll
      for (int cb = 0; cb < 4; ++cb)
#pragma unroll
        for (int r = 0; r < 4; ++r)
          O[cb][q][r] += PA[q * 1024 + (cb * 16 + quad * 4 + r) * 16 + li];
      const float lv = 1.0f / (ls[q] + LSm[(2 * 2 + q) * 16 + li]);
#pragma unroll
      for (int cb = 0; cb < 4; ++cb) {
        union { ushort4 u; short s[4]; } pk_;
#pragma unroll
        for (int r = 0; r < 4; ++r) pk_.s[r] = f2bs(O[cb][q][r] * lv);
        *(ushort4*)&HT[(q * 16 + li) * 72 + cb * 16 + quad * 4] = pk_.u;
      }
    }
  }
  __syncthreads();
  // proj: out[o,n] = wp[o,:] . h'[:,n] + bp[o] + x[o,n]
  short8 Wa[2];
#pragma unroll
  for (int ks = 0; ks < 2; ++ks)
    Wa[ks] = ld8<F32>(wp, (w * 16 + li) * 64 + ks * 32 + quad * 8);
  float bpv[4];
#pragma unroll
  for (int r = 0; r < 4; ++r) bpv[r] = ldx<F32>(bp, w * 16 + quad * 4 + r);
#pragma unroll
  for (int mb = 0; mb < 2; ++mb) {
    short8 Hf[2];
#pragma unroll
    for (int ks = 0; ks < 2; ++ks)
      Hf[ks] = *(const short8*)&HT[(mb * 16 + li) * 72 + ks * 32 + quad * 8];
    f32x4 acc = {0.f, 0.f, 0.f, 0.f};
    acc = mfma32(Wa[0], Hf[0], acc);
    acc = mfma32(Wa[1], Hf[1], acc);
#pragma unroll
    for (int r = 0; r < 4; ++r) {
      const int o = w * 16 + quad * 4 + r;
      const int n = qt * 32 + mb * 16 + li;
      const size_t idx = ((size_t)(b * 64 + o)) * N_ + n;
      const float res = ldx<F32>(xg, idx) + acc[r] + bpv[r];
      if (F32) ((float*)outv)[idx] = res;
      else ((bf16*)outv)[idx] = __float2bfloat16(res);
    }
  }
}

__global__ __launch_bounds__(256, 2) void k_attnproj(
    const bf16* __restrict__ qg, const bf16* __restrict__ kg,
    const bf16* __restrict__ vg, const void* __restrict__ xg,
    const void* __restrict__ wp, const void* __restrict__ bp,
    const int* __restrict__ flag, void* __restrict__ outv) {
  __shared__ __align__(16) short KV[3][8192];
  __shared__ float LSm[3 * 2 * 16];
  const int bid = blockIdx.x;
  const int c = bid & 7, s = bid >> 3;
  const int b = c >> 1, qt = (c & 1) * 64 + s;  // XCD-pair per batch
  if (*flag)
    attnproj_body<true>(qg, kg, vg, xg, wp, bp, outv, KV, LSm, b, qt);
  else
    attnproj_body<false>(qg, kg, vg, xg, wp, bp, outv, KV, LSm, b, qt);
}

// ---------------- launcher --------------------------------------------------
extern "C" void kernel_launch(void* const* d_in, const int* in_sizes, int n_in,
                              void* d_out, int out_size, void* d_ws,
                              size_t ws_size, hipStream_t stream) {
  const void* x = d_in[0];
  const void* wqkv = d_in[1];
  const void* bqkv = d_in[2];
  const void* wproj = d_in[3];
  const void* bproj = d_in[4];

  char* ws = (char*)d_ws;
  float* meanArr = (float*)ws;                      // 1 KB
  float* rstdArr = (float*)(ws + 1024);             // 1 KB
  int* flag = (int*)(ws + 2048);
  bf16* q = (bf16*)(ws + 4096);                     // 2 MB
  bf16* k = (bf16*)(ws + 4096 + (2u << 20));        // 2 MB
  bf16* v = (bf16*)(ws + 4096 + (4u << 20));        // 2 MB

  k_stats<<<256, 256, 0, stream>>>(x, meanArr, rstdArr, flag);
  k_qkv<<<dim3(64, 4), 256, 0, stream>>>(x, wqkv, bqkv, meanArr, rstdArr, q, k,
                                         v, flag);
  k_attnproj<<<512, 256, 0, stream>>>(q, k, v, x, wproj, bproj, flag, d_out);
}

// Round 7
// 117.979 us; speedup vs baseline: 1.0457x; 1.0457x over previous
//
#include <hip/hip_runtime.h>
#include <hip/hip_bf16.h>

#define B_ 4
#define C_ 64
#define N_ 4096
#define EPS_ 1e-5f
// p = exp(s*0.125) = exp2(s * 0.125*log2e); folded into Q at qkv-write time
#define C2_ 0.18033688011112042f

typedef __hip_bfloat16 bf16;
typedef __attribute__((ext_vector_type(8))) short short8;
typedef __attribute__((ext_vector_type(4))) short short4v;
typedef __attribute__((ext_vector_type(4))) float f32x4;

__device__ __forceinline__ float b2f(bf16 v) { return __bfloat162float(v); }

__device__ __forceinline__ short f2bs(float f) {
  union { bf16 h; short s; } u;
  u.h = __float2bfloat16(f);
  return u.s;
}

__device__ __forceinline__ short8 pk8(const float* f) {
  union { short8 v; short s[8]; } u;
#pragma unroll
  for (int i = 0; i < 8; ++i) u.s[i] = f2bs(f[i]);
  return u.v;
}

__device__ __forceinline__ void up8(short8 v, float* d) {
  union { short8 v; unsigned u[4]; } x;
  x.v = v;
  d[0] = __uint_as_float(x.u[0] << 16);
  d[1] = __uint_as_float(x.u[0] & 0xffff0000u);
  d[2] = __uint_as_float(x.u[1] << 16);
  d[3] = __uint_as_float(x.u[1] & 0xffff0000u);
  d[4] = __uint_as_float(x.u[2] << 16);
  d[5] = __uint_as_float(x.u[2] & 0xffff0000u);
  d[6] = __uint_as_float(x.u[3] << 16);
  d[7] = __uint_as_float(x.u[3] & 0xffff0000u);
}

template <bool F32>
__device__ __forceinline__ float ldx(const void* p, size_t idx) {
  if (F32) return ((const float*)p)[idx];
  return b2f(((const bf16*)p)[idx]);
}

template <bool F32>
__device__ __forceinline__ short8 ld8(const void* p, int idx) {
  if (F32) {
    const float* fp = (const float*)p + idx;
    float tmp[8];
    *(float4*)&tmp[0] = *(const float4*)fp;
    *(float4*)&tmp[4] = *(const float4*)(fp + 4);
    return pk8(tmp);
  }
  return *(const short8*)((const bf16*)p + idx);
}

__device__ __forceinline__ f32x4 mfma32(short8 a, short8 b, f32x4 c) {
  return __builtin_amdgcn_mfma_f32_16x16x32_bf16(a, b, c, 0, 0, 0);
}
__device__ __forceinline__ f32x4 mfma16(short4v a, short4v b, f32x4 c) {
  return __builtin_amdgcn_mfma_f32_16x16x16bf16_1k(a, b, c, 0, 0, 0);
}

// Layouts (bf16 element offsets):
// Q  B-frag(K=32): ((b*256+tg)*2+ks)*512 + lane*8 + jj   (k=c, n=token)
// K  A-frag(K=32): ((b*64+kt)*8+jb*2+ks)*512 + lane*8+jj (m=token, k=c)
// V^T A-frag(K=16): ((b*64+kt)*16+cb*4+jb)*256 + lane*4+jj (m=c, k=token)

// ---------------- Kernel 1: stats + integrated dtype probe ------------------
template <bool F32>
__device__ __forceinline__ void stats_sum(const void* x, int bc, int t,
                                          float& s, float& s2) {
  if (F32) {
    const float4* xp = (const float4*)((const float*)x + (size_t)bc * N_);
#pragma unroll
    for (int r = 0; r < 4; ++r) {
      const float4 v = xp[r * 256 + t];
      s += (v.x + v.y) + (v.z + v.w);
      s2 += (v.x * v.x + v.y * v.y) + (v.z * v.z + v.w * v.w);
    }
  } else {
    const bf16* xp = (const bf16*)x + (size_t)bc * N_;
#pragma unroll
    for (int r = 0; r < 2; ++r) {
      float f[8];
      up8(*(const short8*)(xp + (r * 256 + t) * 8), f);
#pragma unroll
      for (int i = 0; i < 8; ++i) { s += f[i]; s2 += f[i] * f[i]; }
    }
  }
}

__global__ __launch_bounds__(256) void k_stats(const void* __restrict__ x,
                                               float* __restrict__ meanArr,
                                               float* __restrict__ rstdArr,
                                               int* __restrict__ flag) {
  const int bc = blockIdx.x, t = threadIdx.x;
  __shared__ float ps[4], ps2[4];
  __shared__ int pflag;
  {
    const ushort* xw = (const ushort*)x + (size_t)bc * 4096;
    int cnt = 0;
#pragma unroll
    for (int j = 0; j < 4; ++j) {
      const ushort4 u = *(const ushort4*)(xw + t * 16 + j * 4);
      cnt += ((u.x >> 7) & 0xFF) >= 143;
      cnt += ((u.y >> 7) & 0xFF) >= 143;
      cnt += ((u.z >> 7) & 0xFF) >= 143;
      cnt += ((u.w >> 7) & 0xFF) >= 143;
    }
#pragma unroll
    for (int off = 32; off > 0; off >>= 1) cnt += __shfl_down(cnt, off, 64);
    if (t == 0) pflag = 0;
    __syncthreads();
    if ((t & 63) == 0 && cnt > 16) atomicAdd(&pflag, cnt);
    __syncthreads();
  }
  const bool f32 = pflag > 64;
  float s = 0.f, s2 = 0.f;
  if (f32) stats_sum<true>(x, bc, t, s, s2);
  else stats_sum<false>(x, bc, t, s, s2);
#pragma unroll
  for (int off = 32; off > 0; off >>= 1) {
    s += __shfl_down(s, off, 64);
    s2 += __shfl_down(s2, off, 64);
  }
  if ((t & 63) == 0) { ps[t >> 6] = s; ps2[t >> 6] = s2; }
  __syncthreads();
  if (t == 0) {
    const float S = (ps[0] + ps[1]) + (ps[2] + ps[3]);
    const float S2 = (ps2[0] + ps2[1]) + (ps2[2] + ps2[3]);
    const float mean = S * (1.0f / N_);
    const float var = S2 * (1.0f / N_) - mean * mean;
    meanArr[bc] = mean;
    rstdArr[bc] = rsqrtf(var + EPS_);
    flag[0] = f32 ? 1 : 0;
  }
}

// ---------------- Kernel 2: norm + qkv projection (MFMA) --------------------
// Q is pre-scaled by C2_ = 0.125*log2(e) so attention uses exp2(sv) directly.
template <bool F32>
__device__ __forceinline__ void qkv_body(const void* x, const void* wqkv,
                                         const void* bqkv, const float* meanArr,
                                         const float* rstdArr, bf16* q, bf16* k,
                                         bf16* v, short* HB) {
  const int t = threadIdx.x, tj = blockIdx.x, b = blockIdx.y;
  const int n0 = tj * 64;
  {
    const int li = t & 15, nbt = (t >> 4) & 3, cg = t >> 6;
    const int n = n0 + nbt * 16 + li;
    const float* mb_ = meanArr + b * 64;
    const float* rb_ = rstdArr + b * 64;
    float hv[16];
#pragma unroll
    for (int i = 0; i < 16; ++i) {
      const int c = cg * 16 + i;
      hv[i] = (ldx<F32>(x, ((size_t)(b * 64 + c)) * N_ + n) - mb_[c]) * rb_[c];
    }
#pragma unroll
    for (int c8 = 0; c8 < 2; ++c8) {
      const int ks = cg >> 1, qd = (cg & 1) * 2 + c8;
      *(short8*)&HB[((nbt * 2 + ks) * 64 + qd * 16 + li) * 8] = pk8(&hv[c8 * 8]);
    }
  }
  __syncthreads();
  const int l = t & 63, w = t >> 6, li = l & 15, quad = l >> 4;
  short8 Wf[3][2];
#pragma unroll
  for (int sec = 0; sec < 3; ++sec)
#pragma unroll
    for (int ks = 0; ks < 2; ++ks)
      Wf[sec][ks] = ld8<F32>(wqkv, (sec * 64 + w * 16 + li) * 64 + ks * 32 + quad * 8);
  short8 Hf[4][2];
#pragma unroll
  for (int nb = 0; nb < 4; ++nb)
#pragma unroll
    for (int ks = 0; ks < 2; ++ks)
      Hf[nb][ks] = *(const short8*)&HB[((nb * 2 + ks) * 64 + l) * 8];
  float bq[4], bk[4];
#pragma unroll
  for (int r = 0; r < 4; ++r) {
    bq[r] = ldx<F32>(bqkv, w * 16 + quad * 4 + r);
    bk[r] = ldx<F32>(bqkv, 64 + w * 16 + quad * 4 + r);
  }
  const float bv = ldx<F32>(bqkv, 128 + w * 16 + li);
  const int lhi = ((w & 1) * 2 + (quad >> 1)) * 16 + li;
  const int jj0 = (quad & 1) * 4;
#pragma unroll
  for (int nb = 0; nb < 4; ++nb) {
    f32x4 dq = {0.f, 0.f, 0.f, 0.f}, dk = dq, dv = dq;
    dq = mfma32(Wf[0][0], Hf[nb][0], dq);
    dq = mfma32(Wf[0][1], Hf[nb][1], dq);
    dk = mfma32(Wf[1][0], Hf[nb][0], dk);
    dk = mfma32(Wf[1][1], Hf[nb][1], dk);
    dv = mfma32(Hf[nb][0], Wf[2][0], dv);
    dv = mfma32(Hf[nb][1], Wf[2][1], dv);
    union { ushort4 u; short s[4]; } pq, pk_, pv;
#pragma unroll
    for (int r = 0; r < 4; ++r) {
      pq.s[r] = f2bs((dq[r] + bq[r]) * C2_);
      pk_.s[r] = f2bs(dk[r] + bk[r]);
      pv.s[r] = f2bs(dv[r] + bv);
    }
    *(ushort4*)&q[(((size_t)(b * 256 + tj * 4 + nb)) * 2 + (w >> 1)) * 512 + lhi * 8 + jj0] = pq.u;
    *(ushort4*)&k[(((size_t)(b * 64 + tj)) * 8 + nb * 2 + (w >> 1)) * 512 + lhi * 8 + jj0] = pk_.u;
    *(ushort4*)&v[(((size_t)(b * 64 + tj)) * 16 + w * 4 + nb) * 256 + (quad * 16 + li) * 4] = pv.u;
  }
}
__global__ __launch_bounds__(256) void k_qkv(
    const void* __restrict__ x, const void* __restrict__ wqkv,
    const void* __restrict__ bqkv, const float* __restrict__ meanArr,
    const float* __restrict__ rstdArr, bf16* __restrict__ q,
    bf16* __restrict__ k, bf16* __restrict__ v, const int* __restrict__ flag) {
  __shared__ short HB[4096];
  if (*flag) qkv_body<true>(x, wqkv, bqkv, meanArr, rstdArr, q, k, v, HB);
  else qkv_body<false>(x, wqkv, bqkv, meanArr, rstdArr, q, k, v, HB);
}

// ---------------- Kernel 3: attention over ALL keys + proj + residual -------
// grid 512 x 512 threads (8 waves). Wave w = (qh = w>>2) * q-group half +
// (jb = w&3) key sub-block. Block owns 32 queries, iterates all 64 K/V
// tiles; K/V staged ONCE per block per tile (same L2 traffic as 4-wave
// version) but 16 waves/CU = 4 waves/SIMD hide the dependent-chain latency.
// Counted-vmcnt 3-deep pipeline (2 loads/thread/tile -> vmcnt(2)).
__device__ __forceinline__ void stage8(short* dst, const bf16* ks_,
                                       const bf16* vs_, int w, int ln) {
  const int off = w * 512;  // wave-uniform LDS base; src is per-lane
  __builtin_amdgcn_global_load_lds(
      (const __attribute__((address_space(1))) unsigned int*)(ks_ + off + ln * 8),
      (__attribute__((address_space(3))) unsigned int*)(dst + off), 16, 0, 0);
  __builtin_amdgcn_global_load_lds(
      (const __attribute__((address_space(1))) unsigned int*)(vs_ + off + ln * 8),
      (__attribute__((address_space(3))) unsigned int*)(dst + 4096 + off), 16, 0, 0);
}

template <bool F32>
__device__ __forceinline__ void attnproj_body(
    const bf16* __restrict__ qg, const bf16* __restrict__ kg,
    const bf16* __restrict__ vg, const void* __restrict__ xg,
    const void* __restrict__ wp, const void* __restrict__ bp,
    void* __restrict__ outv, short (*KV)[8192], float* LSm, int b, int qt) {
  const int t = threadIdx.x, l = t & 63, w = t >> 6, li = l & 15, quad = l >> 4;
  const int jb = w & 3, qh = w >> 2;

  short8 Qf[2];
#pragma unroll
  for (int ks = 0; ks < 2; ++ks)
    Qf[ks] = *(const short8*)(qg +
        (((size_t)(b * 256 + qt * 2 + qh)) * 2 + ks) * 512 + l * 8);

  f32x4 O[4];  // [cb]; C-layout: c = cb*16+quad*4+r, query-col = li
#pragma unroll
  for (int cb = 0; cb < 4; ++cb) O[cb] = {0.f, 0.f, 0.f, 0.f};
  float ls = 0.f;

  const bf16* kbase = kg + ((size_t)(b * 64)) * 4096;
  const bf16* vbase = vg + ((size_t)(b * 64)) * 4096;

  // prologue: 2 tiles in flight (2 loads/thread each)
  stage8(&KV[0][0], kbase, vbase, w, l);
  stage8(&KV[1][0], kbase + 4096, vbase + 4096, w, l);
  int cur = 0;
  for (int it = 0; it < 64; ++it) {
    if (it < 63)
      asm volatile("s_waitcnt vmcnt(2)" ::: "memory");
    else
      asm volatile("s_waitcnt vmcnt(0)" ::: "memory");
    __builtin_amdgcn_s_barrier();
    __builtin_amdgcn_sched_barrier(0);
    if (it + 2 < 64) {
      int nx2 = cur + 2;
      if (nx2 >= 3) nx2 -= 3;
      stage8(&KV[nx2][0], kbase + (size_t)(it + 2) * 4096,
             vbase + (size_t)(it + 2) * 4096, w, l);
    }
    const short* buf = &KV[cur][0];
    short8 Kf[2];
#pragma unroll
    for (int ks = 0; ks < 2; ++ks)
      Kf[ks] = *(const short8*)&buf[(jb * 2 + ks) * 512 + l * 8];
    short4v Vf[4];
#pragma unroll
    for (int cb = 0; cb < 4; ++cb)
      Vf[cb] = *(const short4v*)&buf[4096 + (cb * 4 + jb) * 256 + l * 4];
    f32x4 sv = {0.f, 0.f, 0.f, 0.f};
    sv = mfma32(Kf[0], Qf[0], sv);
    sv = mfma32(Kf[1], Qf[1], sv);
    const float p0 = exp2f(sv[0]), p1 = exp2f(sv[1]);
    const float p2 = exp2f(sv[2]), p3 = exp2f(sv[3]);
    ls += (p0 + p1) + (p2 + p3);
    union { short4v v; __hip_bfloat162 h[2]; } pu;
    pu.h[0] = __float22bfloat162_rn(make_float2(p0, p1));
    pu.h[1] = __float22bfloat162_rn(make_float2(p2, p3));
#pragma unroll
    for (int cb = 0; cb < 4; ++cb)
      O[cb] = mfma16(Vf[cb], pu.v, O[cb]);
    cur = (cur + 1 == 3) ? 0 : cur + 1;
  }
  __syncthreads();  // all compute done; LDS buffers reusable below
  // intra-wave: sum denominator across quads (keys quad-partitioned)
  ls += __shfl_xor(ls, 16, 64);
  ls += __shfl_xor(ls, 32, 64);
  // merge O / ls across the 4 jb-waves per qh, single step via LDS
  float* MB = (float*)&KV[0][0];  // 6 slots x 4KB (jb 1..3 x qh 0..1)
  if (jb != 0) {
    const int ms = (jb - 1) * 2 + qh;
#pragma unroll
    for (int cb = 0; cb < 4; ++cb)
#pragma unroll
      for (int r = 0; r < 4; ++r)
        MB[ms * 1024 + (cb * 16 + quad * 4 + r) * 16 + li] = O[cb][r];
    if (l < 16) LSm[ms * 16 + l] = ls;
  }
  __syncthreads();
  bf16* HT = (bf16*)&KV[2][0];  // h' tile [32 n][72 c] bf16 (72 = pad)
  if (jb == 0) {
#pragma unroll
    for (int j2 = 1; j2 < 4; ++j2) {
      const int ms = (j2 - 1) * 2 + qh;
#pragma unroll
      for (int cb = 0; cb < 4; ++cb)
#pragma unroll
        for (int r = 0; r < 4; ++r)
          O[cb][r] += MB[ms * 1024 + (cb * 16 + quad * 4 + r) * 16 + li];
      ls += LSm[ms * 16 + li];
    }
    const float lv = 1.0f / ls;
#pragma unroll
    for (int cb = 0; cb < 4; ++cb) {
      union { ushort4 u; short s[4]; } pk_;
#pragma unroll
      for (int r = 0; r < 4; ++r) pk_.s[r] = f2bs(O[cb][r] * lv);
      *(ushort4*)&HT[(qh * 16 + li) * 72 + cb * 16 + quad * 4] = pk_.u;
    }
  }
  __syncthreads();
  // proj: out[o,n] = wp[o,:] . h'[:,n] + bp[o] + x[o,n]
  // 8 waves: o-rows (jb) x n-half (qh): each 16 o x 16 n
  short8 Wa[2];
#pragma unroll
  for (int ks = 0; ks < 2; ++ks)
    Wa[ks] = ld8<F32>(wp, (jb * 16 + li) * 64 + ks * 32 + quad * 8);
  float bpv[4];
#pragma unroll
  for (int r = 0; r < 4; ++r) bpv[r] = ldx<F32>(bp, jb * 16 + quad * 4 + r);
  short8 Hf[2];
#pragma unroll
  for (int ks = 0; ks < 2; ++ks)
    Hf[ks] = *(const short8*)&HT[(qh * 16 + li) * 72 + ks * 32 + quad * 8];
  f32x4 acc = {0.f, 0.f, 0.f, 0.f};
  acc = mfma32(Wa[0], Hf[0], acc);
  acc = mfma32(Wa[1], Hf[1], acc);
#pragma unroll
  for (int r = 0; r < 4; ++r) {
    const int o = jb * 16 + quad * 4 + r;
    const int n = qt * 32 + qh * 16 + li;
    const size_t idx = ((size_t)(b * 64 + o)) * N_ + n;
    const float res = ldx<F32>(xg, idx) + acc[r] + bpv[r];
    if (F32) ((float*)outv)[idx] = res;
    else ((bf16*)outv)[idx] = __float2bfloat16(res);
  }
}

__global__ __launch_bounds__(512, 4) void k_attnproj(
    const bf16* __restrict__ qg, const bf16* __restrict__ kg,
    const bf16* __restrict__ vg, const void* __restrict__ xg,
    const void* __restrict__ wp, const void* __restrict__ bp,
    const int* __restrict__ flag, void* __restrict__ outv) {
  __shared__ __align__(16) short KV[3][8192];
  __shared__ float LSm[6 * 16];
  const int bid = blockIdx.x;
  const int c = bid & 7, s = bid >> 3;
  const int b = c >> 1, qt = (c & 1) * 64 + s;  // XCD-pair per batch
  if (*flag)
    attnproj_body<true>(qg, kg, vg, xg, wp, bp, outv, KV, LSm, b, qt);
  else
    attnproj_body<false>(qg, kg, vg, xg, wp, bp, outv, KV, LSm, b, qt);
}

// ---------------- launcher --------------------------------------------------
extern "C" void kernel_launch(void* const* d_in, const int* in_sizes, int n_in,
                              void* d_out, int out_size, void* d_ws,
                              size_t ws_size, hipStream_t stream) {
  const void* x = d_in[0];
  const void* wqkv = d_in[1];
  const void* bqkv = d_in[2];
  const void* wproj = d_in[3];
  const void* bproj = d_in[4];

  char* ws = (char*)d_ws;
  float* meanArr = (float*)ws;                      // 1 KB
  float* rstdArr = (float*)(ws + 1024);             // 1 KB
  int* flag = (int*)(ws + 2048);
  bf16* q = (bf16*)(ws + 4096);                     // 2 MB
  bf16* k = (bf16*)(ws + 4096 + (2u << 20));        // 2 MB
  bf16* v = (bf16*)(ws + 4096 + (4u << 20));        // 2 MB

  k_stats<<<256, 256, 0, stream>>>(x, meanArr, rstdArr, flag);
  k_qkv<<<dim3(64, 4), 256, 0, stream>>>(x, wqkv, bqkv, meanArr, rstdArr, q, k,
                                         v, flag);
  k_attnproj<<<512, 512, 0, stream>>>(q, k, v, x, wproj, bproj, flag, d_out);
}

// Round 8
// 101.538 us; speedup vs baseline: 1.2150x; 1.1619x over previous
//
#include <hip/hip_runtime.h>
#include <hip/hip_bf16.h>

#define B_ 4
#define C_ 64
#define N_ 4096
#define EPS_ 1e-5f
// p = exp(s*0.125) = exp2(s * 0.125*log2e); folded into Q at qkv-write time
#define C2_ 0.18033688011112042f

typedef __hip_bfloat16 bf16;
typedef __attribute__((ext_vector_type(8))) short short8;
typedef __attribute__((ext_vector_type(4))) float f32x4;
typedef __attribute__((ext_vector_type(16))) float f32x16;

__device__ __forceinline__ float b2f(bf16 v) { return __bfloat162float(v); }

__device__ __forceinline__ short f2bs(float f) {
  union { bf16 h; short s; } u;
  u.h = __float2bfloat16(f);
  return u.s;
}

__device__ __forceinline__ short8 pk8(const float* f) {
  union { short8 v; short s[8]; } u;
#pragma unroll
  for (int i = 0; i < 8; ++i) u.s[i] = f2bs(f[i]);
  return u.v;
}

__device__ __forceinline__ void up8(short8 v, float* d) {
  union { short8 v; unsigned u[4]; } x;
  x.v = v;
  d[0] = __uint_as_float(x.u[0] << 16);
  d[1] = __uint_as_float(x.u[0] & 0xffff0000u);
  d[2] = __uint_as_float(x.u[1] << 16);
  d[3] = __uint_as_float(x.u[1] & 0xffff0000u);
  d[4] = __uint_as_float(x.u[2] << 16);
  d[5] = __uint_as_float(x.u[2] & 0xffff0000u);
  d[6] = __uint_as_float(x.u[3] << 16);
  d[7] = __uint_as_float(x.u[3] & 0xffff0000u);
}

template <bool F32>
__device__ __forceinline__ float ldx(const void* p, size_t idx) {
  if (F32) return ((const float*)p)[idx];
  return b2f(((const bf16*)p)[idx]);
}

template <bool F32>
__device__ __forceinline__ short8 ld8(const void* p, int idx) {
  if (F32) {
    const float* fp = (const float*)p + idx;
    float tmp[8];
    *(float4*)&tmp[0] = *(const float4*)fp;
    *(float4*)&tmp[4] = *(const float4*)(fp + 4);
    return pk8(tmp);
  }
  return *(const short8*)((const bf16*)p + idx);
}

__device__ __forceinline__ f32x4 mfma32(short8 a, short8 b, f32x4 c) {
  return __builtin_amdgcn_mfma_f32_16x16x32_bf16(a, b, c, 0, 0, 0);
}
__device__ __forceinline__ f32x16 mfmaL(short8 a, short8 b, f32x16 c) {
  return __builtin_amdgcn_mfma_f32_32x32x16_bf16(a, b, c, 0, 0, 0);
}

// ---- Workspace layouts (bf16 element offsets), 32x32x16-frag native ----
// Q [b][qt32][chunk4][hi2][q'32][jj8]   (B-frag: n=l&31, k=(l>>5)*8+jj)
// K [b][kh32][chunk4][hi2][key'32][jj8] (A-frag: m=l&31, k=(l>>5)*8+jj)
// V [b][kc16][ch2][hi2][c'32][jj8], keys bit-permuted (koff bits 2<->3) so
//   the PV B-frag is cvt_pk of QK output regs in-order (no cross-lane).

// ---------------- Kernel 1: stats + integrated dtype probe ------------------
template <bool F32>
__device__ __forceinline__ void stats_sum(const void* x, int bc, int t,
                                          float& s, float& s2) {
  if (F32) {
    const float4* xp = (const float4*)((const float*)x + (size_t)bc * N_);
#pragma unroll
    for (int r = 0; r < 4; ++r) {
      const float4 v = xp[r * 256 + t];
      s += (v.x + v.y) + (v.z + v.w);
      s2 += (v.x * v.x + v.y * v.y) + (v.z * v.z + v.w * v.w);
    }
  } else {
    const bf16* xp = (const bf16*)x + (size_t)bc * N_;
#pragma unroll
    for (int r = 0; r < 2; ++r) {
      float f[8];
      up8(*(const short8*)(xp + (r * 256 + t) * 8), f);
#pragma unroll
      for (int i = 0; i < 8; ++i) { s += f[i]; s2 += f[i] * f[i]; }
    }
  }
}

__global__ __launch_bounds__(256) void k_stats(const void* __restrict__ x,
                                               float* __restrict__ meanArr,
                                               float* __restrict__ rstdArr,
                                               int* __restrict__ flag) {
  const int bc = blockIdx.x, t = threadIdx.x;
  __shared__ float ps[4], ps2[4];
  __shared__ int pflag;
  {
    const ushort* xw = (const ushort*)x + (size_t)bc * 4096;
    int cnt = 0;
#pragma unroll
    for (int j = 0; j < 4; ++j) {
      const ushort4 u = *(const ushort4*)(xw + t * 16 + j * 4);
      cnt += ((u.x >> 7) & 0xFF) >= 143;
      cnt += ((u.y >> 7) & 0xFF) >= 143;
      cnt += ((u.z >> 7) & 0xFF) >= 143;
      cnt += ((u.w >> 7) & 0xFF) >= 143;
    }
#pragma unroll
    for (int off = 32; off > 0; off >>= 1) cnt += __shfl_down(cnt, off, 64);
    if (t == 0) pflag = 0;
    __syncthreads();
    if ((t & 63) == 0 && cnt > 16) atomicAdd(&pflag, cnt);
    __syncthreads();
  }
  const bool f32 = pflag > 64;
  float s = 0.f, s2 = 0.f;
  if (f32) stats_sum<true>(x, bc, t, s, s2);
  else stats_sum<false>(x, bc, t, s, s2);
#pragma unroll
  for (int off = 32; off > 0; off >>= 1) {
    s += __shfl_down(s, off, 64);
    s2 += __shfl_down(s2, off, 64);
  }
  if ((t & 63) == 0) { ps[t >> 6] = s; ps2[t >> 6] = s2; }
  __syncthreads();
  if (t == 0) {
    const float S = (ps[0] + ps[1]) + (ps[2] + ps[3]);
    const float S2 = (ps2[0] + ps2[1]) + (ps2[2] + ps2[3]);
    const float mean = S * (1.0f / N_);
    const float var = S2 * (1.0f / N_) - mean * mean;
    meanArr[bc] = mean;
    rstdArr[bc] = rsqrtf(var + EPS_);
    flag[0] = f32 ? 1 : 0;
  }
}

// ---------------- Kernel 2: norm + qkv projection (MFMA) --------------------
// Q pre-scaled by C2_. Writes q/k/v in the 32x32-frag layouts above.
template <bool F32>
__device__ __forceinline__ void qkv_body(const void* x, const void* wqkv,
                                         const void* bqkv, const float* meanArr,
                                         const float* rstdArr, bf16* q, bf16* k,
                                         bf16* v, short* HB) {
  const int t = threadIdx.x, tj = blockIdx.x, b = blockIdx.y;
  const int n0 = tj * 64;
  {
    const int li = t & 15, nbt = (t >> 4) & 3, cg = t >> 6;
    const int n = n0 + nbt * 16 + li;
    const float* mb_ = meanArr + b * 64;
    const float* rb_ = rstdArr + b * 64;
    float hv[16];
#pragma unroll
    for (int i = 0; i < 16; ++i) {
      const int c = cg * 16 + i;
      hv[i] = (ldx<F32>(x, ((size_t)(b * 64 + c)) * N_ + n) - mb_[c]) * rb_[c];
    }
#pragma unroll
    for (int c8 = 0; c8 < 2; ++c8) {
      const int ks = cg >> 1, qd = (cg & 1) * 2 + c8;
      *(short8*)&HB[((nbt * 2 + ks) * 64 + qd * 16 + li) * 8] = pk8(&hv[c8 * 8]);
    }
  }
  __syncthreads();
  const int l = t & 63, w = t >> 6, li = l & 15, quad = l >> 4;
  short8 Wf[3][2];
#pragma unroll
  for (int sec = 0; sec < 3; ++sec)
#pragma unroll
    for (int ks = 0; ks < 2; ++ks)
      Wf[sec][ks] = ld8<F32>(wqkv, (sec * 64 + w * 16 + li) * 64 + ks * 32 + quad * 8);
  short8 Hf[4][2];
#pragma unroll
  for (int nb = 0; nb < 4; ++nb)
#pragma unroll
    for (int ks = 0; ks < 2; ++ks)
      Hf[nb][ks] = *(const short8*)&HB[((nb * 2 + ks) * 64 + l) * 8];
  float bq[4], bk[4];
#pragma unroll
  for (int r = 0; r < 4; ++r) {
    bq[r] = ldx<F32>(bqkv, w * 16 + quad * 4 + r);
    bk[r] = ldx<F32>(bqkv, 64 + w * 16 + quad * 4 + r);
  }
  const float bv = ldx<F32>(bqkv, 128 + w * 16 + li);
#pragma unroll
  for (int nb = 0; nb < 4; ++nb) {
    f32x4 dq = {0.f, 0.f, 0.f, 0.f}, dk = dq, dv = dq;
    dq = mfma32(Wf[0][0], Hf[nb][0], dq);
    dq = mfma32(Wf[0][1], Hf[nb][1], dq);
    dk = mfma32(Wf[1][0], Hf[nb][0], dk);
    dk = mfma32(Wf[1][1], Hf[nb][1], dk);
    dv = mfma32(Hf[nb][0], Wf[2][0], dv);
    dv = mfma32(Hf[nb][1], Wf[2][1], dv);
    union { ushort4 u; short s[4]; } pq, pk_, pv;
#pragma unroll
    for (int r = 0; r < 4; ++r) {
      pq.s[r] = f2bs((dq[r] + bq[r]) * C2_);
      pk_.s[r] = f2bs(dk[r] + bk[r]);
      pv.s[r] = f2bs(dv[r] + bv);
    }
    const int nbg = tj * 4 + nb;
    // q/k: lane holds X[c_out = w*16+quad*4+r][token = nb*16+li]
    //   qt32/kh32 = nbg>>1; q'/key' = (nbg&1)*16+li; chunk=w;
    //   hi = quad>>1; jj = (quad&1)*4 + r  (consecutive r -> ushort4)
    const size_t qko = ((((size_t)(b * 128 + (nbg >> 1))) * 4 + w) * 2 +
                        (quad >> 1)) * 256 +
                       ((nbg & 1) * 16 + li) * 8 + (quad & 1) * 4;
    *(ushort4*)&q[qko] = pq.u;
    *(ushort4*)&k[qko] = pk_.u;
    // v: lane holds V[c_out = w*16+li][token = nb*16+quad*4+r]
    //   kc = nbg; ch = w>>1; c' = (w&1)*16+li; koff = quad*4+r
    //   key slot s = r + (quad&2)*2 + (quad&1)*8 (bits 2<->3 swap)
    const size_t vo = ((((size_t)(b * 256 + nbg)) * 2 + (w >> 1)) * 2 +
                       (quad & 1)) * 256 +
                      ((w & 1) * 16 + li) * 8 + (quad & 2) * 2;
    *(ushort4*)&v[vo] = pv.u;
  }
}
__global__ __launch_bounds__(256) void k_qkv(
    const void* __restrict__ x, const void* __restrict__ wqkv,
    const void* __restrict__ bqkv, const float* __restrict__ meanArr,
    const float* __restrict__ rstdArr, bf16* __restrict__ q,
    bf16* __restrict__ k, bf16* __restrict__ v, const int* __restrict__ flag) {
  __shared__ short HB[4096];
  if (*flag) qkv_body<true>(x, wqkv, bqkv, meanArr, rstdArr, q, k, v, HB);
  else qkv_body<false>(x, wqkv, bqkv, meanArr, rstdArr, q, k, v, HB);
}

// ---------------- Kernel 3: barrier-free attention + proj + residual --------
// grid 256 = (b, qt64), 512 thr / 8 waves. Wave w streams 32-key chunks
// ci = w, w+8, ..., w+120 with K/V fragments loaded straight to VGPRs
// (ping-pong, 2 chunks in flight -> compiler-counted vmcnt, NO barriers).
// Each fragment is reused for both 32-query halves (qs), halving traffic.
// 32x32x16 MFMA: 4 QK + 8 PV per chunk. End: LDS tree-merge + proj.
template <bool F32>
__device__ __forceinline__ void attnproj_body(
    const bf16* __restrict__ qg, const bf16* __restrict__ kg,
    const bf16* __restrict__ vg, const void* __restrict__ xg,
    const void* __restrict__ wp, const void* __restrict__ bp,
    void* __restrict__ outv, float* MS, float* LSs, int b, int qt) {
  const int t = threadIdx.x, l = t & 63, w = t >> 6;
  const int hi = l >> 5, q31 = l & 31;

  short8 Qf[2][4];
#pragma unroll
  for (int qs = 0; qs < 2; ++qs)
#pragma unroll
    for (int cc = 0; cc < 4; ++cc)
      Qf[qs][cc] = *(const short8*)(qg +
          ((((size_t)(b * 128 + qt * 2 + qs)) * 4 + cc) * 2 + hi) * 256 +
          q31 * 8);

  f32x16 O[2][2];
#pragma unroll
  for (int qs = 0; qs < 2; ++qs)
#pragma unroll
    for (int ch = 0; ch < 2; ++ch)
#pragma unroll
      for (int r = 0; r < 16; ++r) O[qs][ch][r] = 0.f;
  float ls[2] = {0.f, 0.f};

  const bf16* kb = kg + ((size_t)b * 128) * 2048;  // per kh32: 4*2*256 = 2048
  const bf16* vb = vg + ((size_t)b * 256) * 1024;  // per kc16: 2*2*256 = 1024

  short8 Kf[2][4], Vf[2][4];
#pragma unroll
  for (int p = 0; p < 2; ++p) {
    const int ci = w + p * 8;
#pragma unroll
    for (int cc = 0; cc < 4; ++cc)
      Kf[p][cc] = *(const short8*)(kb + (((size_t)ci * 4 + cc) * 2 + hi) * 256 + q31 * 8);
#pragma unroll
    for (int i = 0; i < 4; ++i)
      Vf[p][i] = *(const short8*)(vb + (((size_t)(ci * 2 + (i >> 1)) * 2 + (i & 1)) * 2 + hi) * 256 + q31 * 8);
  }

  for (int j = 0; j < 16; j += 2) {
#pragma unroll
    for (int p = 0; p < 2; ++p) {
      const int jp = j + p;
      const int ci = w + 8 * jp;
      const bool pf = jp < 14;
      f32x16 sv[2];
#pragma unroll
      for (int qs = 0; qs < 2; ++qs) {
#pragma unroll
        for (int r = 0; r < 16; ++r) sv[qs][r] = 0.f;
#pragma unroll
        for (int cc = 0; cc < 4; ++cc)
          sv[qs] = mfmaL(Kf[p][cc], Qf[qs][cc], sv[qs]);
      }
      if (pf) {
        const int cn = ci + 16;
#pragma unroll
        for (int cc = 0; cc < 4; ++cc)
          Kf[p][cc] = *(const short8*)(kb + (((size_t)cn * 4 + cc) * 2 + hi) * 256 + q31 * 8);
      }
      short8 Pb[2][2];
#pragma unroll
      for (int qs = 0; qs < 2; ++qs) {
        float pv[16];
#pragma unroll
        for (int r = 0; r < 16; ++r) pv[r] = exp2f(sv[qs][r]);
        ls[qs] += (((pv[0] + pv[1]) + (pv[2] + pv[3])) +
                   ((pv[4] + pv[5]) + (pv[6] + pv[7]))) +
                  (((pv[8] + pv[9]) + (pv[10] + pv[11])) +
                   ((pv[12] + pv[13]) + (pv[14] + pv[15])));
        union { short8 v; __hip_bfloat162 h[4]; } u0, u1;
#pragma unroll
        for (int wd = 0; wd < 4; ++wd) {
          u0.h[wd] = __float22bfloat162_rn(make_float2(pv[2 * wd], pv[2 * wd + 1]));
          u1.h[wd] = __float22bfloat162_rn(make_float2(pv[8 + 2 * wd], pv[9 + 2 * wd]));
        }
        Pb[qs][0] = u0.v;
        Pb[qs][1] = u1.v;
      }
#pragma unroll
      for (int qs = 0; qs < 2; ++qs)
#pragma unroll
        for (int ch = 0; ch < 2; ++ch)
#pragma unroll
          for (int kc2 = 0; kc2 < 2; ++kc2)
            O[qs][ch] = mfmaL(Vf[p][kc2 * 2 + ch], Pb[qs][kc2], O[qs][ch]);
      if (pf) {
        const int cn = ci + 16;
#pragma unroll
        for (int i = 0; i < 4; ++i)
          Vf[p][i] = *(const short8*)(vb + (((size_t)(cn * 2 + (i >> 1)) * 2 + (i & 1)) * 2 + hi) * 256 + q31 * 8);
      }
    }
  }
  // lane l covers hi-half keys; lane l^32 (same q) covers the other half
#pragma unroll
  for (int qs = 0; qs < 2; ++qs) ls[qs] += __shfl_xor(ls[qs], 32, 64);

  // tree merge across 8 waves (LDS slots of 16KB; ls alongside)
  if (w >= 4) {
    float* S = MS + (w - 4) * 4096;
#pragma unroll
    for (int qs = 0; qs < 2; ++qs) {
#pragma unroll
      for (int ch = 0; ch < 2; ++ch)
#pragma unroll
        for (int r = 0; r < 16; ++r)
          S[((qs * 2 + ch) * 16 + r) * 64 + l] = O[qs][ch][r];
      LSs[(w - 4) * 128 + qs * 64 + l] = ls[qs];
    }
  }
  __syncthreads();
  if (w < 4) {
    const float* S = MS + w * 4096;
#pragma unroll
    for (int qs = 0; qs < 2; ++qs) {
#pragma unroll
      for (int ch = 0; ch < 2; ++ch)
#pragma unroll
        for (int r = 0; r < 16; ++r)
          O[qs][ch][r] += S[((qs * 2 + ch) * 16 + r) * 64 + l];
      ls[qs] += LSs[w * 128 + qs * 64 + l];
    }
  }
  __syncthreads();
  if (w == 2 || w == 3) {
    float* S = MS + (w - 2) * 4096;
#pragma unroll
    for (int qs = 0; qs < 2; ++qs) {
#pragma unroll
      for (int ch = 0; ch < 2; ++ch)
#pragma unroll
        for (int r = 0; r < 16; ++r)
          S[((qs * 2 + ch) * 16 + r) * 64 + l] = O[qs][ch][r];
      LSs[(w - 2) * 128 + qs * 64 + l] = ls[qs];
    }
  }
  __syncthreads();
  if (w < 2) {
    const float* S = MS + w * 4096;
#pragma unroll
    for (int qs = 0; qs < 2; ++qs) {
#pragma unroll
      for (int ch = 0; ch < 2; ++ch)
#pragma unroll
        for (int r = 0; r < 16; ++r)
          O[qs][ch][r] += S[((qs * 2 + ch) * 16 + r) * 64 + l];
      ls[qs] += LSs[w * 128 + qs * 64 + l];
    }
  }
  __syncthreads();
  if (w == 1) {
    float* S = MS;
#pragma unroll
    for (int qs = 0; qs < 2; ++qs) {
#pragma unroll
      for (int ch = 0; ch < 2; ++ch)
#pragma unroll
        for (int r = 0; r < 16; ++r)
          S[((qs * 2 + ch) * 16 + r) * 64 + l] = O[qs][ch][r];
      LSs[qs * 64 + l] = ls[qs];
    }
  }
  __syncthreads();
  bf16* HT = (bf16*)(MS + 2 * 4096);  // slot2 region (dead): h' [64 q][72 c]
  if (w == 0) {
    const float* S = MS;
#pragma unroll
    for (int qs = 0; qs < 2; ++qs) {
#pragma unroll
      for (int ch = 0; ch < 2; ++ch)
#pragma unroll
        for (int r = 0; r < 16; ++r)
          O[qs][ch][r] += S[((qs * 2 + ch) * 16 + r) * 64 + l];
      ls[qs] += LSs[qs * 64 + l];
      const float lv = 1.0f / ls[qs];
      const int qrow = qs * 32 + q31;
#pragma unroll
      for (int ch = 0; ch < 2; ++ch)
#pragma unroll
        for (int g = 0; g < 4; ++g) {
          union { ushort4 u; short s[4]; } pk_;
#pragma unroll
          for (int rr = 0; rr < 4; ++rr)
            pk_.s[rr] = f2bs(O[qs][ch][g * 4 + rr] * lv);
          // c = ch*32 + (r&3) + 8*(r>>2) + 4*hi
          *(ushort4*)&HT[qrow * 72 + ch * 32 + g * 8 + hi * 4] = pk_.u;
        }
    }
  }
  __syncthreads();
  // proj: out[o,n] = wp[o,:] . h'[:,n] + bp[o] + x[o,n]; 8 waves: (jb o) x (qh n)
  const int li = l & 15, quad = l >> 4;
  const int jb = w & 3, qh = w >> 2;
  short8 Wa[2];
#pragma unroll
  for (int ks = 0; ks < 2; ++ks)
    Wa[ks] = ld8<F32>(wp, (jb * 16 + li) * 64 + ks * 32 + quad * 8);
  float bpv[4];
#pragma unroll
  for (int r = 0; r < 4; ++r) bpv[r] = ldx<F32>(bp, jb * 16 + quad * 4 + r);
#pragma unroll
  for (int nb = 0; nb < 2; ++nb) {
    short8 Hf[2];
#pragma unroll
    for (int ks = 0; ks < 2; ++ks)
      Hf[ks] = *(const short8*)&HT[(qh * 32 + nb * 16 + li) * 72 + ks * 32 + quad * 8];
    f32x4 acc = {0.f, 0.f, 0.f, 0.f};
    acc = mfma32(Wa[0], Hf[0], acc);
    acc = mfma32(Wa[1], Hf[1], acc);
#pragma unroll
    for (int r = 0; r < 4; ++r) {
      const int o = jb * 16 + quad * 4 + r;
      const int n = qt * 64 + qh * 32 + nb * 16 + li;
      const size_t idx = ((size_t)(b * 64 + o)) * N_ + n;
      const float res = ldx<F32>(xg, idx) + acc[r] + bpv[r];
      if (F32) ((float*)outv)[idx] = res;
      else ((bf16*)outv)[idx] = __float2bfloat16(res);
    }
  }
}

__global__ __launch_bounds__(512, 2) void k_attnproj(
    const bf16* __restrict__ qg, const bf16* __restrict__ kg,
    const bf16* __restrict__ vg, const void* __restrict__ xg,
    const void* __restrict__ wp, const void* __restrict__ bp,
    const int* __restrict__ flag, void* __restrict__ outv) {
  __shared__ float MS[4 * 4096];   // 64 KB merge slots (slot2 reused as HT)
  __shared__ float LSs[4 * 128];   // 2 KB ls slots
  const int bid = blockIdx.x;
  const int x = bid & 7;            // XCD: each XCD serves one batch's K/V
  const int b = x >> 1, qt = (bid >> 3) * 2 + (x & 1);
  if (*flag)
    attnproj_body<true>(qg, kg, vg, xg, wp, bp, outv, MS, LSs, b, qt);
  else
    attnproj_body<false>(qg, kg, vg, xg, wp, bp, outv, MS, LSs, b, qt);
}

// ---------------- launcher --------------------------------------------------
extern "C" void kernel_launch(void* const* d_in, const int* in_sizes, int n_in,
                              void* d_out, int out_size, void* d_ws,
                              size_t ws_size, hipStream_t stream) {
  const void* x = d_in[0];
  const void* wqkv = d_in[1];
  const void* bqkv = d_in[2];
  const void* wproj = d_in[3];
  const void* bproj = d_in[4];

  char* ws = (char*)d_ws;
  float* meanArr = (float*)ws;                      // 1 KB
  float* rstdArr = (float*)(ws + 1024);             // 1 KB
  int* flag = (int*)(ws + 2048);
  bf16* q = (bf16*)(ws + 4096);                     // 2 MB
  bf16* k = (bf16*)(ws + 4096 + (2u << 20));        // 2 MB
  bf16* v = (bf16*)(ws + 4096 + (4u << 20));        // 2 MB

  k_stats<<<256, 256, 0, stream>>>(x, meanArr, rstdArr, flag);
  k_qkv<<<dim3(64, 4), 256, 0, stream>>>(x, wqkv, bqkv, meanArr, rstdArr, q, k,
                                         v, flag);
  k_attnproj<<<256, 512, 0, stream>>>(q, k, v, x, wproj, bproj, flag, d_out);
}

// Round 9
// 98.496 us; speedup vs baseline: 1.2525x; 1.0309x over previous
//
#include <hip/hip_runtime.h>
#include <hip/hip_bf16.h>

#define B_ 4
#define C_ 64
#define N_ 4096
#define EPS_ 1e-5f
// p = exp(s*0.125) = exp2(s * 0.125*log2e); folded into Q at qkv-write time
#define C2_ 0.18033688011112042f

typedef __hip_bfloat16 bf16;
typedef __attribute__((ext_vector_type(8))) short short8;
typedef __attribute__((ext_vector_type(4))) float f32x4;
typedef __attribute__((ext_vector_type(16))) float f32x16;

__device__ __forceinline__ float b2f(bf16 v) { return __bfloat162float(v); }

__device__ __forceinline__ short f2bs(float f) {
  union { bf16 h; short s; } u;
  u.h = __float2bfloat16(f);
  return u.s;
}

__device__ __forceinline__ short8 pk8(const float* f) {
  union { short8 v; short s[8]; } u;
#pragma unroll
  for (int i = 0; i < 8; ++i) u.s[i] = f2bs(f[i]);
  return u.v;
}

__device__ __forceinline__ void up8(short8 v, float* d) {
  union { short8 v; unsigned u[4]; } x;
  x.v = v;
  d[0] = __uint_as_float(x.u[0] << 16);
  d[1] = __uint_as_float(x.u[0] & 0xffff0000u);
  d[2] = __uint_as_float(x.u[1] << 16);
  d[3] = __uint_as_float(x.u[1] & 0xffff0000u);
  d[4] = __uint_as_float(x.u[2] << 16);
  d[5] = __uint_as_float(x.u[2] & 0xffff0000u);
  d[6] = __uint_as_float(x.u[3] << 16);
  d[7] = __uint_as_float(x.u[3] & 0xffff0000u);
}

template <bool F32>
__device__ __forceinline__ float ldx(const void* p, size_t idx) {
  if (F32) return ((const float*)p)[idx];
  return b2f(((const bf16*)p)[idx]);
}

template <bool F32>
__device__ __forceinline__ short8 ld8(const void* p, int idx) {
  if (F32) {
    const float* fp = (const float*)p + idx;
    float tmp[8];
    *(float4*)&tmp[0] = *(const float4*)fp;
    *(float4*)&tmp[4] = *(const float4*)(fp + 4);
    return pk8(tmp);
  }
  return *(const short8*)((const bf16*)p + idx);
}

__device__ __forceinline__ f32x4 mfma32(short8 a, short8 b, f32x4 c) {
  return __builtin_amdgcn_mfma_f32_16x16x32_bf16(a, b, c, 0, 0, 0);
}
__device__ __forceinline__ f32x16 mfmaL(short8 a, short8 b, f32x16 c) {
  return __builtin_amdgcn_mfma_f32_32x32x16_bf16(a, b, c, 0, 0, 0);
}

// ---- Workspace layouts (bf16 element offsets), 32x32x16-frag native ----
// Q [b][qt32][chunk4][hi2][q'32][jj8]   (B-frag: n=l&31, k=(l>>5)*8+jj)
// K [b][kh32][chunk4][hi2][key'32][jj8] (A-frag: m=l&31, k=(l>>5)*8+jj)
// V [b][kc16][ch2][hi2][c'32][jj8], keys bit-permuted (koff bits 2<->3) so
//   the PV B-frag is cvt_pk of QK output regs in-order (no cross-lane).

// ---------------- Kernel 1: stats + integrated dtype probe ------------------
template <bool F32>
__device__ __forceinline__ void stats_sum(const void* x, int bc, int t,
                                          float& s, float& s2) {
  if (F32) {
    const float4* xp = (const float4*)((const float*)x + (size_t)bc * N_);
#pragma unroll
    for (int r = 0; r < 4; ++r) {
      const float4 v = xp[r * 256 + t];
      s += (v.x + v.y) + (v.z + v.w);
      s2 += (v.x * v.x + v.y * v.y) + (v.z * v.z + v.w * v.w);
    }
  } else {
    const bf16* xp = (const bf16*)x + (size_t)bc * N_;
#pragma unroll
    for (int r = 0; r < 2; ++r) {
      float f[8];
      up8(*(const short8*)(xp + (r * 256 + t) * 8), f);
#pragma unroll
      for (int i = 0; i < 8; ++i) { s += f[i]; s2 += f[i] * f[i]; }
    }
  }
}

__global__ __launch_bounds__(256) void k_stats(const void* __restrict__ x,
                                               float* __restrict__ meanArr,
                                               float* __restrict__ rstdArr,
                                               int* __restrict__ flag) {
  const int bc = blockIdx.x, t = threadIdx.x;
  __shared__ float ps[4], ps2[4];
  __shared__ int pflag;
  {
    const ushort* xw = (const ushort*)x + (size_t)bc * 4096;
    int cnt = 0;
#pragma unroll
    for (int j = 0; j < 4; ++j) {
      const ushort4 u = *(const ushort4*)(xw + t * 16 + j * 4);
      cnt += ((u.x >> 7) & 0xFF) >= 143;
      cnt += ((u.y >> 7) & 0xFF) >= 143;
      cnt += ((u.z >> 7) & 0xFF) >= 143;
      cnt += ((u.w >> 7) & 0xFF) >= 143;
    }
#pragma unroll
    for (int off = 32; off > 0; off >>= 1) cnt += __shfl_down(cnt, off, 64);
    if (t == 0) pflag = 0;
    __syncthreads();
    if ((t & 63) == 0 && cnt > 16) atomicAdd(&pflag, cnt);
    __syncthreads();
  }
  const bool f32 = pflag > 64;
  float s = 0.f, s2 = 0.f;
  if (f32) stats_sum<true>(x, bc, t, s, s2);
  else stats_sum<false>(x, bc, t, s, s2);
#pragma unroll
  for (int off = 32; off > 0; off >>= 1) {
    s += __shfl_down(s, off, 64);
    s2 += __shfl_down(s2, off, 64);
  }
  if ((t & 63) == 0) { ps[t >> 6] = s; ps2[t >> 6] = s2; }
  __syncthreads();
  if (t == 0) {
    const float S = (ps[0] + ps[1]) + (ps[2] + ps[3]);
    const float S2 = (ps2[0] + ps2[1]) + (ps2[2] + ps2[3]);
    const float mean = S * (1.0f / N_);
    const float var = S2 * (1.0f / N_) - mean * mean;
    meanArr[bc] = mean;
    rstdArr[bc] = rsqrtf(var + EPS_);
    flag[0] = f32 ? 1 : 0;
  }
}

// ---------------- Kernel 2: norm + qkv projection (MFMA) --------------------
// Q pre-scaled by C2_. Writes q/k/v in the 32x32-frag layouts above.
template <bool F32>
__device__ __forceinline__ void qkv_body(const void* x, const void* wqkv,
                                         const void* bqkv, const float* meanArr,
                                         const float* rstdArr, bf16* q, bf16* k,
                                         bf16* v, short* HB) {
  const int t = threadIdx.x, tj = blockIdx.x, b = blockIdx.y;
  const int n0 = tj * 64;
  {
    const int li = t & 15, nbt = (t >> 4) & 3, cg = t >> 6;
    const int n = n0 + nbt * 16 + li;
    const float* mb_ = meanArr + b * 64;
    const float* rb_ = rstdArr + b * 64;
    float hv[16];
#pragma unroll
    for (int i = 0; i < 16; ++i) {
      const int c = cg * 16 + i;
      hv[i] = (ldx<F32>(x, ((size_t)(b * 64 + c)) * N_ + n) - mb_[c]) * rb_[c];
    }
#pragma unroll
    for (int c8 = 0; c8 < 2; ++c8) {
      const int ks = cg >> 1, qd = (cg & 1) * 2 + c8;
      *(short8*)&HB[((nbt * 2 + ks) * 64 + qd * 16 + li) * 8] = pk8(&hv[c8 * 8]);
    }
  }
  __syncthreads();
  const int l = t & 63, w = t >> 6, li = l & 15, quad = l >> 4;
  short8 Wf[3][2];
#pragma unroll
  for (int sec = 0; sec < 3; ++sec)
#pragma unroll
    for (int ks = 0; ks < 2; ++ks)
      Wf[sec][ks] = ld8<F32>(wqkv, (sec * 64 + w * 16 + li) * 64 + ks * 32 + quad * 8);
  short8 Hf[4][2];
#pragma unroll
  for (int nb = 0; nb < 4; ++nb)
#pragma unroll
    for (int ks = 0; ks < 2; ++ks)
      Hf[nb][ks] = *(const short8*)&HB[((nb * 2 + ks) * 64 + l) * 8];
  float bq[4], bk[4];
#pragma unroll
  for (int r = 0; r < 4; ++r) {
    bq[r] = ldx<F32>(bqkv, w * 16 + quad * 4 + r);
    bk[r] = ldx<F32>(bqkv, 64 + w * 16 + quad * 4 + r);
  }
  const float bv = ldx<F32>(bqkv, 128 + w * 16 + li);
#pragma unroll
  for (int nb = 0; nb < 4; ++nb) {
    f32x4 dq = {0.f, 0.f, 0.f, 0.f}, dk = dq, dv = dq;
    dq = mfma32(Wf[0][0], Hf[nb][0], dq);
    dq = mfma32(Wf[0][1], Hf[nb][1], dq);
    dk = mfma32(Wf[1][0], Hf[nb][0], dk);
    dk = mfma32(Wf[1][1], Hf[nb][1], dk);
    dv = mfma32(Hf[nb][0], Wf[2][0], dv);
    dv = mfma32(Hf[nb][1], Wf[2][1], dv);
    union { ushort4 u; short s[4]; } pq, pk_, pv;
#pragma unroll
    for (int r = 0; r < 4; ++r) {
      pq.s[r] = f2bs((dq[r] + bq[r]) * C2_);
      pk_.s[r] = f2bs(dk[r] + bk[r]);
      pv.s[r] = f2bs(dv[r] + bv);
    }
    const int nbg = tj * 4 + nb;
    // q/k: lane holds X[c_out = w*16+quad*4+r][token = nb*16+li]
    const size_t qko = ((((size_t)(b * 128 + (nbg >> 1))) * 4 + w) * 2 +
                        (quad >> 1)) * 256 +
                       ((nbg & 1) * 16 + li) * 8 + (quad & 1) * 4;
    *(ushort4*)&q[qko] = pq.u;
    *(ushort4*)&k[qko] = pk_.u;
    // v: lane holds V[c_out = w*16+li][token = nb*16+quad*4+r]
    const size_t vo = ((((size_t)(b * 256 + nbg)) * 2 + (w >> 1)) * 2 +
                       (quad & 1)) * 256 +
                      ((w & 1) * 16 + li) * 8 + (quad & 2) * 2;
    *(ushort4*)&v[vo] = pv.u;
  }
}
__global__ __launch_bounds__(256) void k_qkv(
    const void* __restrict__ x, const void* __restrict__ wqkv,
    const void* __restrict__ bqkv, const float* __restrict__ meanArr,
    const float* __restrict__ rstdArr, bf16* __restrict__ q,
    bf16* __restrict__ k, bf16* __restrict__ v, const int* __restrict__ flag) {
  __shared__ short HB[4096];
  if (*flag) qkv_body<true>(x, wqkv, bqkv, meanArr, rstdArr, q, k, v, HB);
  else qkv_body<false>(x, wqkv, bqkv, meanArr, rstdArr, q, k, v, HB);
}

// ---------------- Kernel 3: barrier-free attention + proj + residual --------
// grid 256 = (b, qt64), 512 thr / 8 waves. Wave w streams 32-key chunks
// ci = w, w+8, ..., w+120; K/V fragments load straight to VGPRs, SINGLE
// buffered (register diet: ~200 VGPR live, no scratch). Schedule per chunk:
// QK(0) -> exp/pack(0) -> QK(1) [Kf last use] -> prefetch K(next) ->
// exp/pack(1) -> PV(0)+PV(1) [Vf last use] -> prefetch V(next).
// Prefetch distance >= ~400 cyc covers L2 latency. NO barriers in loop.
template <bool F32>
__device__ __forceinline__ void attnproj_body(
    const bf16* __restrict__ qg, const bf16* __restrict__ kg,
    const bf16* __restrict__ vg, const void* __restrict__ xg,
    const void* __restrict__ wp, const void* __restrict__ bp,
    void* __restrict__ outv, float* MS, float* LSs, int b, int qt) {
  const int t = threadIdx.x, l = t & 63, w = t >> 6;
  const int hi = l >> 5, q31 = l & 31;

  short8 Qf[2][4];
#pragma unroll
  for (int qs = 0; qs < 2; ++qs)
#pragma unroll
    for (int cc = 0; cc < 4; ++cc)
      Qf[qs][cc] = *(const short8*)(qg +
          ((((size_t)(b * 128 + qt * 2 + qs)) * 4 + cc) * 2 + hi) * 256 +
          q31 * 8);

  f32x16 O[2][2];
#pragma unroll
  for (int qs = 0; qs < 2; ++qs)
#pragma unroll
    for (int ch = 0; ch < 2; ++ch)
#pragma unroll
      for (int r = 0; r < 16; ++r) O[qs][ch][r] = 0.f;
  float ls[2] = {0.f, 0.f};

  const bf16* kb = kg + ((size_t)b * 128) * 2048;  // per kh32: 4*2*256 = 2048
  const bf16* vb = vg + ((size_t)b * 256) * 1024;  // per kc16: 2*2*256 = 1024

  short8 Kf[4], Vf[4];
#pragma unroll
  for (int cc = 0; cc < 4; ++cc)
    Kf[cc] = *(const short8*)(kb + (((size_t)w * 4 + cc) * 2 + hi) * 256 + q31 * 8);
#pragma unroll
  for (int i = 0; i < 4; ++i)
    Vf[i] = *(const short8*)(vb + (((size_t)(w * 2 + (i >> 1)) * 2 + (i & 1)) * 2 + hi) * 256 + q31 * 8);

  for (int jp = 0; jp < 16; ++jp) {
    const int cn = w + 8 * (jp + 1);
    const bool pf = jp < 15;
    // ---- QK qs=0
    f32x16 sv;
#pragma unroll
    for (int r = 0; r < 16; ++r) sv[r] = 0.f;
#pragma unroll
    for (int cc = 0; cc < 4; ++cc) sv = mfmaL(Kf[cc], Qf[0][cc], sv);
    // ---- softmax numerators qs=0
    short8 Pb0[2];
    {
      float pv[16];
#pragma unroll
      for (int r = 0; r < 16; ++r) pv[r] = exp2f(sv[r]);
      ls[0] += (((pv[0] + pv[1]) + (pv[2] + pv[3])) +
                ((pv[4] + pv[5]) + (pv[6] + pv[7]))) +
               (((pv[8] + pv[9]) + (pv[10] + pv[11])) +
                ((pv[12] + pv[13]) + (pv[14] + pv[15])));
      union { short8 v; __hip_bfloat162 h[4]; } u0, u1;
#pragma unroll
      for (int wd = 0; wd < 4; ++wd) {
        u0.h[wd] = __float22bfloat162_rn(make_float2(pv[2 * wd], pv[2 * wd + 1]));
        u1.h[wd] = __float22bfloat162_rn(make_float2(pv[8 + 2 * wd], pv[9 + 2 * wd]));
      }
      Pb0[0] = u0.v;
      Pb0[1] = u1.v;
    }
    // ---- QK qs=1 (last read of Kf)
#pragma unroll
    for (int r = 0; r < 16; ++r) sv[r] = 0.f;
#pragma unroll
    for (int cc = 0; cc < 4; ++cc) sv = mfmaL(Kf[cc], Qf[1][cc], sv);
    // ---- prefetch K(next) into the single buffer
    if (pf) {
#pragma unroll
      for (int cc = 0; cc < 4; ++cc)
        Kf[cc] = *(const short8*)(kb + (((size_t)cn * 4 + cc) * 2 + hi) * 256 + q31 * 8);
    }
    // ---- softmax numerators qs=1
    short8 Pb1[2];
    {
      float pv[16];
#pragma unroll
      for (int r = 0; r < 16; ++r) pv[r] = exp2f(sv[r]);
      ls[1] += (((pv[0] + pv[1]) + (pv[2] + pv[3])) +
                ((pv[4] + pv[5]) + (pv[6] + pv[7]))) +
               (((pv[8] + pv[9]) + (pv[10] + pv[11])) +
                ((pv[12] + pv[13]) + (pv[14] + pv[15])));
      union { short8 v; __hip_bfloat162 h[4]; } u0, u1;
#pragma unroll
      for (int wd = 0; wd < 4; ++wd) {
        u0.h[wd] = __float22bfloat162_rn(make_float2(pv[2 * wd], pv[2 * wd + 1]));
        u1.h[wd] = __float22bfloat162_rn(make_float2(pv[8 + 2 * wd], pv[9 + 2 * wd]));
      }
      Pb1[0] = u0.v;
      Pb1[1] = u1.v;
    }
    // ---- PV both query-sets (last read of Vf)
#pragma unroll
    for (int ch = 0; ch < 2; ++ch)
#pragma unroll
      for (int kc2 = 0; kc2 < 2; ++kc2) {
        O[0][ch] = mfmaL(Vf[kc2 * 2 + ch], Pb0[kc2], O[0][ch]);
        O[1][ch] = mfmaL(Vf[kc2 * 2 + ch], Pb1[kc2], O[1][ch]);
      }
    // ---- prefetch V(next)
    if (pf) {
#pragma unroll
      for (int i = 0; i < 4; ++i)
        Vf[i] = *(const short8*)(vb + (((size_t)(cn * 2 + (i >> 1)) * 2 + (i & 1)) * 2 + hi) * 256 + q31 * 8);
    }
  }
  // lane l covers hi-half keys; lane l^32 (same q) covers the other half
#pragma unroll
  for (int qs = 0; qs < 2; ++qs) ls[qs] += __shfl_xor(ls[qs], 32, 64);

  // tree merge across 8 waves (LDS slots of 16KB; ls alongside)
  if (w >= 4) {
    float* S = MS + (w - 4) * 4096;
#pragma unroll
    for (int qs = 0; qs < 2; ++qs) {
#pragma unroll
      for (int ch = 0; ch < 2; ++ch)
#pragma unroll
        for (int r = 0; r < 16; ++r)
          S[((qs * 2 + ch) * 16 + r) * 64 + l] = O[qs][ch][r];
      LSs[(w - 4) * 128 + qs * 64 + l] = ls[qs];
    }
  }
  __syncthreads();
  if (w < 4) {
    const float* S = MS + w * 4096;
#pragma unroll
    for (int qs = 0; qs < 2; ++qs) {
#pragma unroll
      for (int ch = 0; ch < 2; ++ch)
#pragma unroll
        for (int r = 0; r < 16; ++r)
          O[qs][ch][r] += S[((qs * 2 + ch) * 16 + r) * 64 + l];
      ls[qs] += LSs[w * 128 + qs * 64 + l];
    }
  }
  __syncthreads();
  if (w == 2 || w == 3) {
    float* S = MS + (w - 2) * 4096;
#pragma unroll
    for (int qs = 0; qs < 2; ++qs) {
#pragma unroll
      for (int ch = 0; ch < 2; ++ch)
#pragma unroll
        for (int r = 0; r < 16; ++r)
          S[((qs * 2 + ch) * 16 + r) * 64 + l] = O[qs][ch][r];
      LSs[(w - 2) * 128 + qs * 64 + l] = ls[qs];
    }
  }
  __syncthreads();
  if (w < 2) {
    const float* S = MS + w * 4096;
#pragma unroll
    for (int qs = 0; qs < 2; ++qs) {
#pragma unroll
      for (int ch = 0; ch < 2; ++ch)
#pragma unroll
        for (int r = 0; r < 16; ++r)
          O[qs][ch][r] += S[((qs * 2 + ch) * 16 + r) * 64 + l];
      ls[qs] += LSs[w * 128 + qs * 64 + l];
    }
  }
  __syncthreads();
  if (w == 1) {
    float* S = MS;
#pragma unroll
    for (int qs = 0; qs < 2; ++qs) {
#pragma unroll
      for (int ch = 0; ch < 2; ++ch)
#pragma unroll
        for (int r = 0; r < 16; ++r)
          S[((qs * 2 + ch) * 16 + r) * 64 + l] = O[qs][ch][r];
      LSs[qs * 64 + l] = ls[qs];
    }
  }
  __syncthreads();
  bf16* HT = (bf16*)(MS + 2 * 4096);  // slot2 region (dead): h' [64 q][72 c]
  if (w == 0) {
    const float* S = MS;
#pragma unroll
    for (int qs = 0; qs < 2; ++qs) {
#pragma unroll
      for (int ch = 0; ch < 2; ++ch)
#pragma unroll
        for (int r = 0; r < 16; ++r)
          O[qs][ch][r] += S[((qs * 2 + ch) * 16 + r) * 64 + l];
      ls[qs] += LSs[qs * 64 + l];
      const float lv = 1.0f / ls[qs];
      const int qrow = qs * 32 + q31;
#pragma unroll
      for (int ch = 0; ch < 2; ++ch)
#pragma unroll
        for (int g = 0; g < 4; ++g) {
          union { ushort4 u; short s[4]; } pk_;
#pragma unroll
          for (int rr = 0; rr < 4; ++rr)
            pk_.s[rr] = f2bs(O[qs][ch][g * 4 + rr] * lv);
          // c = ch*32 + (r&3) + 8*(r>>2) + 4*hi
          *(ushort4*)&HT[qrow * 72 + ch * 32 + g * 8 + hi * 4] = pk_.u;
        }
    }
  }
  __syncthreads();
  // proj: out[o,n] = wp[o,:] . h'[:,n] + bp[o] + x[o,n]; 8 waves: (jb o) x (qh n)
  const int li = l & 15, quad = l >> 4;
  const int jb = w & 3, qh = w >> 2;
  short8 Wa[2];
#pragma unroll
  for (int ks = 0; ks < 2; ++ks)
    Wa[ks] = ld8<F32>(wp, (jb * 16 + li) * 64 + ks * 32 + quad * 8);
  float bpv[4];
#pragma unroll
  for (int r = 0; r < 4; ++r) bpv[r] = ldx<F32>(bp, jb * 16 + quad * 4 + r);
#pragma unroll
  for (int nb = 0; nb < 2; ++nb) {
    short8 Hf[2];
#pragma unroll
    for (int ks = 0; ks < 2; ++ks)
      Hf[ks] = *(const short8*)&HT[(qh * 32 + nb * 16 + li) * 72 + ks * 32 + quad * 8];
    f32x4 acc = {0.f, 0.f, 0.f, 0.f};
    acc = mfma32(Wa[0], Hf[0], acc);
    acc = mfma32(Wa[1], Hf[1], acc);
#pragma unroll
    for (int r = 0; r < 4; ++r) {
      const int o = jb * 16 + quad * 4 + r;
      const int n = qt * 64 + qh * 32 + nb * 16 + li;
      const size_t idx = ((size_t)(b * 64 + o)) * N_ + n;
      const float res = ldx<F32>(xg, idx) + acc[r] + bpv[r];
      if (F32) ((float*)outv)[idx] = res;
      else ((bf16*)outv)[idx] = __float2bfloat16(res);
    }
  }
}

__global__ __launch_bounds__(512, 2) void k_attnproj(
    const bf16* __restrict__ qg, const bf16* __restrict__ kg,
    const bf16* __restrict__ vg, const void* __restrict__ xg,
    const void* __restrict__ wp, const void* __restrict__ bp,
    const int* __restrict__ flag, void* __restrict__ outv) {
  __shared__ float MS[4 * 4096];   // 64 KB merge slots (slot2 reused as HT)
  __shared__ float LSs[4 * 128];   // 2 KB ls slots
  const int bid = blockIdx.x;
  const int x = bid & 7;            // XCD: each XCD pair serves one batch
  const int b = x >> 1, qt = (bid >> 3) * 2 + (x & 1);
  if (*flag)
    attnproj_body<true>(qg, kg, vg, xg, wp, bp, outv, MS, LSs, b, qt);
  else
    attnproj_body<false>(qg, kg, vg, xg, wp, bp, outv, MS, LSs, b, qt);
}

// ---------------- launcher --------------------------------------------------
extern "C" void kernel_launch(void* const* d_in, const int* in_sizes, int n_in,
                              void* d_out, int out_size, void* d_ws,
                              size_t ws_size, hipStream_t stream) {
  const void* x = d_in[0];
  const void* wqkv = d_in[1];
  const void* bqkv = d_in[2];
  const void* wproj = d_in[3];
  const void* bproj = d_in[4];

  char* ws = (char*)d_ws;
  float* meanArr = (float*)ws;                      // 1 KB
  float* rstdArr = (float*)(ws + 1024);             // 1 KB
  int* flag = (int*)(ws + 2048);
  bf16* q = (bf16*)(ws + 4096);                     // 2 MB
  bf16* k = (bf16*)(ws + 4096 + (2u << 20));        // 2 MB
  bf16* v = (bf16*)(ws + 4096 + (4u << 20));        // 2 MB

  k_stats<<<256, 256, 0, stream>>>(x, meanArr, rstdArr, flag);
  k_qkv<<<dim3(64, 4), 256, 0, stream>>>(x, wqkv, bqkv, meanArr, rstdArr, q, k,
                                         v, flag);
  k_attnproj<<<256, 512, 0, stream>>>(q, k, v, x, wproj, bproj, flag, d_out);
}

// Round 10
// 92.469 us; speedup vs baseline: 1.3342x; 1.0652x over previous
//
#include <hip/hip_runtime.h>
#include <hip/hip_bf16.h>

#define B_ 4
#define C_ 64
#define N_ 4096
#define EPS_ 1e-5f
// p = exp(s*0.125) = exp2(s * 0.125*log2e); folded into Q at qkv-write time
#define C2_ 0.18033688011112042f

#if __has_builtin(__builtin_amdgcn_exp2f)
#define EXP2(x) __builtin_amdgcn_exp2f(x)
#else
#define EXP2(x) exp2f(x)
#endif

typedef __hip_bfloat16 bf16;
typedef __attribute__((ext_vector_type(8))) short short8;
typedef __attribute__((ext_vector_type(4))) float f32x4;
typedef __attribute__((ext_vector_type(16))) float f32x16;

__device__ __forceinline__ float b2f(bf16 v) { return __bfloat162float(v); }

__device__ __forceinline__ short f2bs(float f) {
  union { bf16 h; short s; } u;
  u.h = __float2bfloat16(f);
  return u.s;
}

__device__ __forceinline__ short8 pk8(const float* f) {
  union { short8 v; short s[8]; } u;
#pragma unroll
  for (int i = 0; i < 8; ++i) u.s[i] = f2bs(f[i]);
  return u.v;
}

__device__ __forceinline__ void up8(short8 v, float* d) {
  union { short8 v; unsigned u[4]; } x;
  x.v = v;
  d[0] = __uint_as_float(x.u[0] << 16);
  d[1] = __uint_as_float(x.u[0] & 0xffff0000u);
  d[2] = __uint_as_float(x.u[1] << 16);
  d[3] = __uint_as_float(x.u[1] & 0xffff0000u);
  d[4] = __uint_as_float(x.u[2] << 16);
  d[5] = __uint_as_float(x.u[2] & 0xffff0000u);
  d[6] = __uint_as_float(x.u[3] << 16);
  d[7] = __uint_as_float(x.u[3] & 0xffff0000u);
}

template <bool F32>
__device__ __forceinline__ float ldx(const void* p, size_t idx) {
  if (F32) return ((const float*)p)[idx];
  return b2f(((const bf16*)p)[idx]);
}

template <bool F32>
__device__ __forceinline__ short8 ld8(const void* p, int idx) {
  if (F32) {
    const float* fp = (const float*)p + idx;
    float tmp[8];
    *(float4*)&tmp[0] = *(const float4*)fp;
    *(float4*)&tmp[4] = *(const float4*)(fp + 4);
    return pk8(tmp);
  }
  return *(const short8*)((const bf16*)p + idx);
}

__device__ __forceinline__ f32x4 mfma32(short8 a, short8 b, f32x4 c) {
  return __builtin_amdgcn_mfma_f32_16x16x32_bf16(a, b, c, 0, 0, 0);
}
__device__ __forceinline__ f32x16 mfmaL(short8 a, short8 b, f32x16 c) {
  return __builtin_amdgcn_mfma_f32_32x32x16_bf16(a, b, c, 0, 0, 0);
}

// ---- Workspace layouts (bf16 element offsets), 32x32x16-frag native ----
// Q [b][qt32][chunk4][hi2][q'32][jj8]   (B-frag: n=l&31, k=(l>>5)*8+jj)
// K [b][kh32][chunk4][hi2][key'32][jj8] (A-frag: m=l&31, k=(l>>5)*8+jj)
// V [b][kc16][ch2][hi2][c'32][jj8], keys bit-permuted (koff bits 2<->3) so
//   the PV B-frag is cvt_pk of QK output regs in-order (no cross-lane).

// ---------------- Kernel 1: stats + integrated dtype probe ------------------
template <bool F32>
__device__ __forceinline__ void stats_sum(const void* x, int bc, int t,
                                          float& s, float& s2) {
  if (F32) {
    const float4* xp = (const float4*)((const float*)x + (size_t)bc * N_);
#pragma unroll
    for (int r = 0; r < 4; ++r) {
      const float4 v = xp[r * 256 + t];
      s += (v.x + v.y) + (v.z + v.w);
      s2 += (v.x * v.x + v.y * v.y) + (v.z * v.z + v.w * v.w);
    }
  } else {
    const bf16* xp = (const bf16*)x + (size_t)bc * N_;
#pragma unroll
    for (int r = 0; r < 2; ++r) {
      float f[8];
      up8(*(const short8*)(xp + (r * 256 + t) * 8), f);
#pragma unroll
      for (int i = 0; i < 8; ++i) { s += f[i]; s2 += f[i] * f[i]; }
    }
  }
}

__global__ __launch_bounds__(256) void k_stats(const void* __restrict__ x,
                                               float* __restrict__ meanArr,
                                               float* __restrict__ rstdArr,
                                               int* __restrict__ flag) {
  const int bc = blockIdx.x, t = threadIdx.x;
  __shared__ float ps[4], ps2[4];
  __shared__ int pflag;
  {
    const ushort* xw = (const ushort*)x + (size_t)bc * 4096;
    int cnt = 0;
#pragma unroll
    for (int j = 0; j < 4; ++j) {
      const ushort4 u = *(const ushort4*)(xw + t * 16 + j * 4);
      cnt += ((u.x >> 7) & 0xFF) >= 143;
      cnt += ((u.y >> 7) & 0xFF) >= 143;
      cnt += ((u.z >> 7) & 0xFF) >= 143;
      cnt += ((u.w >> 7) & 0xFF) >= 143;
    }
#pragma unroll
    for (int off = 32; off > 0; off >>= 1) cnt += __shfl_down(cnt, off, 64);
    if (t == 0) pflag = 0;
    __syncthreads();
    if ((t & 63) == 0 && cnt > 16) atomicAdd(&pflag, cnt);
    __syncthreads();
  }
  const bool f32 = pflag > 64;
  float s = 0.f, s2 = 0.f;
  if (f32) stats_sum<true>(x, bc, t, s, s2);
  else stats_sum<false>(x, bc, t, s, s2);
#pragma unroll
  for (int off = 32; off > 0; off >>= 1) {
    s += __shfl_down(s, off, 64);
    s2 += __shfl_down(s2, off, 64);
  }
  if ((t & 63) == 0) { ps[t >> 6] = s; ps2[t >> 6] = s2; }
  __syncthreads();
  if (t == 0) {
    const float S = (ps[0] + ps[1]) + (ps[2] + ps[3]);
    const float S2 = (ps2[0] + ps2[1]) + (ps2[2] + ps2[3]);
    const float mean = S * (1.0f / N_);
    const float var = S2 * (1.0f / N_) - mean * mean;
    meanArr[bc] = mean;
    rstdArr[bc] = rsqrtf(var + EPS_);
    flag[0] = f32 ? 1 : 0;
  }
}

// ---------------- Kernel 2: norm + qkv projection (MFMA) --------------------
// Q pre-scaled by C2_. Writes q/k/v in the 32x32-frag layouts above.
template <bool F32>
__device__ __forceinline__ void qkv_body(const void* x, const void* wqkv,
                                         const void* bqkv, const float* meanArr,
                                         const float* rstdArr, bf16* q, bf16* k,
                                         bf16* v, short* HB) {
  const int t = threadIdx.x, tj = blockIdx.x, b = blockIdx.y;
  const int n0 = tj * 64;
  {
    const int li = t & 15, nbt = (t >> 4) & 3, cg = t >> 6;
    const int n = n0 + nbt * 16 + li;
    const float* mb_ = meanArr + b * 64;
    const float* rb_ = rstdArr + b * 64;
    float hv[16];
#pragma unroll
    for (int i = 0; i < 16; ++i) {
      const int c = cg * 16 + i;
      hv[i] = (ldx<F32>(x, ((size_t)(b * 64 + c)) * N_ + n) - mb_[c]) * rb_[c];
    }
#pragma unroll
    for (int c8 = 0; c8 < 2; ++c8) {
      const int ks = cg >> 1, qd = (cg & 1) * 2 + c8;
      *(short8*)&HB[((nbt * 2 + ks) * 64 + qd * 16 + li) * 8] = pk8(&hv[c8 * 8]);
    }
  }
  __syncthreads();
  const int l = t & 63, w = t >> 6, li = l & 15, quad = l >> 4;
  short8 Wf[3][2];
#pragma unroll
  for (int sec = 0; sec < 3; ++sec)
#pragma unroll
    for (int ks = 0; ks < 2; ++ks)
      Wf[sec][ks] = ld8<F32>(wqkv, (sec * 64 + w * 16 + li) * 64 + ks * 32 + quad * 8);
  short8 Hf[4][2];
#pragma unroll
  for (int nb = 0; nb < 4; ++nb)
#pragma unroll
    for (int ks = 0; ks < 2; ++ks)
      Hf[nb][ks] = *(const short8*)&HB[((nb * 2 + ks) * 64 + l) * 8];
  float bq[4], bk[4];
#pragma unroll
  for (int r = 0; r < 4; ++r) {
    bq[r] = ldx<F32>(bqkv, w * 16 + quad * 4 + r);
    bk[r] = ldx<F32>(bqkv, 64 + w * 16 + quad * 4 + r);
  }
  const float bv = ldx<F32>(bqkv, 128 + w * 16 + li);
#pragma unroll
  for (int nb = 0; nb < 4; ++nb) {
    f32x4 dq = {0.f, 0.f, 0.f, 0.f}, dk = dq, dv = dq;
    dq = mfma32(Wf[0][0], Hf[nb][0], dq);
    dq = mfma32(Wf[0][1], Hf[nb][1], dq);
    dk = mfma32(Wf[1][0], Hf[nb][0], dk);
    dk = mfma32(Wf[1][1], Hf[nb][1], dk);
    dv = mfma32(Hf[nb][0], Wf[2][0], dv);
    dv = mfma32(Hf[nb][1], Wf[2][1], dv);
    union { ushort4 u; short s[4]; } pq, pk_, pv;
#pragma unroll
    for (int r = 0; r < 4; ++r) {
      pq.s[r] = f2bs((dq[r] + bq[r]) * C2_);
      pk_.s[r] = f2bs(dk[r] + bk[r]);
      pv.s[r] = f2bs(dv[r] + bv);
    }
    const int nbg = tj * 4 + nb;
    // q/k: lane holds X[c_out = w*16+quad*4+r][token = nb*16+li]
    const size_t qko = ((((size_t)(b * 128 + (nbg >> 1))) * 4 + w) * 2 +
                        (quad >> 1)) * 256 +
                       ((nbg & 1) * 16 + li) * 8 + (quad & 1) * 4;
    *(ushort4*)&q[qko] = pq.u;
    *(ushort4*)&k[qko] = pk_.u;
    // v: lane holds V[c_out = w*16+li][token = nb*16+quad*4+r]
    const size_t vo = ((((size_t)(b * 256 + nbg)) * 2 + (w >> 1)) * 2 +
                       (quad & 1)) * 256 +
                      ((w & 1) * 16 + li) * 8 + (quad & 2) * 2;
    *(ushort4*)&v[vo] = pv.u;
  }
}
__global__ __launch_bounds__(256) void k_qkv(
    const void* __restrict__ x, const void* __restrict__ wqkv,
    const void* __restrict__ bqkv, const float* __restrict__ meanArr,
    const float* __restrict__ rstdArr, bf16* __restrict__ q,
    bf16* __restrict__ k, bf16* __restrict__ v, const int* __restrict__ flag) {
  __shared__ short HB[4096];
  if (*flag) qkv_body<true>(x, wqkv, bqkv, meanArr, rstdArr, q, k, v, HB);
  else qkv_body<false>(x, wqkv, bqkv, meanArr, rstdArr, q, k, v, HB);
}

// ---------------- Kernel 3: barrier-free attention + proj + residual --------
// grid 256 = (b, qt64), 512 thr / 8 waves. Wave w streams 32-key chunks
// ci = w, w+8, ..., w+120; K/V fragments load straight to VGPRs, single
// buffered. Per chunk: interleaved QK chains (sv0,sv1 overlap MFMA latency)
// -> prefetch K(next) -> exp(raw v_exp_f32)+pack both -> PV cluster under
// setprio(1) -> prefetch V(next). NO barriers in the loop.
template <bool F32>
__device__ __forceinline__ void attnproj_body(
    const bf16* __restrict__ qg, const bf16* __restrict__ kg,
    const bf16* __restrict__ vg, const void* __restrict__ xg,
    const void* __restrict__ wp, const void* __restrict__ bp,
    void* __restrict__ outv, float* MS, float* LSs, int b, int qt) {
  const int t = threadIdx.x, l = t & 63, w = t >> 6;
  const int hi = l >> 5, q31 = l & 31;

  short8 Qf[2][4];
#pragma unroll
  for (int qs = 0; qs < 2; ++qs)
#pragma unroll
    for (int cc = 0; cc < 4; ++cc)
      Qf[qs][cc] = *(const short8*)(qg +
          ((((size_t)(b * 128 + qt * 2 + qs)) * 4 + cc) * 2 + hi) * 256 +
          q31 * 8);

  f32x16 O[2][2];
#pragma unroll
  for (int qs = 0; qs < 2; ++qs)
#pragma unroll
    for (int ch = 0; ch < 2; ++ch)
#pragma unroll
      for (int r = 0; r < 16; ++r) O[qs][ch][r] = 0.f;
  float ls[2] = {0.f, 0.f};

  const bf16* kb = kg + ((size_t)b * 128) * 2048;  // per kh32: 4*2*256 = 2048
  const bf16* vb = vg + ((size_t)b * 256) * 1024;  // per kc16: 2*2*256 = 1024

  short8 Kf[4], Vf[4];
#pragma unroll
  for (int cc = 0; cc < 4; ++cc)
    Kf[cc] = *(const short8*)(kb + (((size_t)w * 4 + cc) * 2 + hi) * 256 + q31 * 8);
#pragma unroll
  for (int i = 0; i < 4; ++i)
    Vf[i] = *(const short8*)(vb + (((size_t)(w * 2 + (i >> 1)) * 2 + (i & 1)) * 2 + hi) * 256 + q31 * 8);

  for (int jp = 0; jp < 16; ++jp) {
    const int cn = w + 8 * (jp + 1);
    const bool pf = jp < 15;
    // ---- interleaved QK chains for both query-sets (independent MFMA deps)
    f32x16 sv0, sv1;
#pragma unroll
    for (int r = 0; r < 16; ++r) { sv0[r] = 0.f; sv1[r] = 0.f; }
#pragma unroll
    for (int cc = 0; cc < 4; ++cc) {
      sv0 = mfmaL(Kf[cc], Qf[0][cc], sv0);
      sv1 = mfmaL(Kf[cc], Qf[1][cc], sv1);
    }
    // ---- prefetch K(next) (Kf regs free after QK)
    if (pf) {
#pragma unroll
      for (int cc = 0; cc < 4; ++cc)
        Kf[cc] = *(const short8*)(kb + (((size_t)cn * 4 + cc) * 2 + hi) * 256 + q31 * 8);
    }
    // ---- softmax numerators (raw v_exp_f32) + bf16 pack, both query-sets
    short8 Pb0[2], Pb1[2];
    {
      float pv[16];
#pragma unroll
      for (int r = 0; r < 16; ++r) pv[r] = EXP2(sv0[r]);
      ls[0] += (((pv[0] + pv[1]) + (pv[2] + pv[3])) +
                ((pv[4] + pv[5]) + (pv[6] + pv[7]))) +
               (((pv[8] + pv[9]) + (pv[10] + pv[11])) +
                ((pv[12] + pv[13]) + (pv[14] + pv[15])));
      union { short8 v; __hip_bfloat162 h[4]; } u0, u1;
#pragma unroll
      for (int wd = 0; wd < 4; ++wd) {
        u0.h[wd] = __float22bfloat162_rn(make_float2(pv[2 * wd], pv[2 * wd + 1]));
        u1.h[wd] = __float22bfloat162_rn(make_float2(pv[8 + 2 * wd], pv[9 + 2 * wd]));
      }
      Pb0[0] = u0.v;
      Pb0[1] = u1.v;
    }
    {
      float pv[16];
#pragma unroll
      for (int r = 0; r < 16; ++r) pv[r] = EXP2(sv1[r]);
      ls[1] += (((pv[0] + pv[1]) + (pv[2] + pv[3])) +
                ((pv[4] + pv[5]) + (pv[6] + pv[7]))) +
               (((pv[8] + pv[9]) + (pv[10] + pv[11])) +
                ((pv[12] + pv[13]) + (pv[14] + pv[15])));
      union { short8 v; __hip_bfloat162 h[4]; } u0, u1;
#pragma unroll
      for (int wd = 0; wd < 4; ++wd) {
        u0.h[wd] = __float22bfloat162_rn(make_float2(pv[2 * wd], pv[2 * wd + 1]));
        u1.h[wd] = __float22bfloat162_rn(make_float2(pv[8 + 2 * wd], pv[9 + 2 * wd]));
      }
      Pb1[0] = u0.v;
      Pb1[1] = u1.v;
    }
    // ---- PV cluster (last read of Vf) under raised wave priority
    __builtin_amdgcn_s_setprio(1);
#pragma unroll
    for (int ch = 0; ch < 2; ++ch)
#pragma unroll
      for (int kc2 = 0; kc2 < 2; ++kc2) {
        O[0][ch] = mfmaL(Vf[kc2 * 2 + ch], Pb0[kc2], O[0][ch]);
        O[1][ch] = mfmaL(Vf[kc2 * 2 + ch], Pb1[kc2], O[1][ch]);
      }
    __builtin_amdgcn_s_setprio(0);
    // ---- prefetch V(next)
    if (pf) {
#pragma unroll
      for (int i = 0; i < 4; ++i)
        Vf[i] = *(const short8*)(vb + (((size_t)(cn * 2 + (i >> 1)) * 2 + (i & 1)) * 2 + hi) * 256 + q31 * 8);
    }
  }
  // lane l covers hi-half keys; lane l^32 (same q) covers the other half
#pragma unroll
  for (int qs = 0; qs < 2; ++qs) ls[qs] += __shfl_xor(ls[qs], 32, 64);

  // tree merge across 8 waves (LDS slots of 16KB; ls alongside)
  if (w >= 4) {
    float* S = MS + (w - 4) * 4096;
#pragma unroll
    for (int qs = 0; qs < 2; ++qs) {
#pragma unroll
      for (int ch = 0; ch < 2; ++ch)
#pragma unroll
        for (int r = 0; r < 16; ++r)
          S[((qs * 2 + ch) * 16 + r) * 64 + l] = O[qs][ch][r];
      LSs[(w - 4) * 128 + qs * 64 + l] = ls[qs];
    }
  }
  __syncthreads();
  if (w < 4) {
    const float* S = MS + w * 4096;
#pragma unroll
    for (int qs = 0; qs < 2; ++qs) {
#pragma unroll
      for (int ch = 0; ch < 2; ++ch)
#pragma unroll
        for (int r = 0; r < 16; ++r)
          O[qs][ch][r] += S[((qs * 2 + ch) * 16 + r) * 64 + l];
      ls[qs] += LSs[w * 128 + qs * 64 + l];
    }
  }
  __syncthreads();
  if (w == 2 || w == 3) {
    float* S = MS + (w - 2) * 4096;
#pragma unroll
    for (int qs = 0; qs < 2; ++qs) {
#pragma unroll
      for (int ch = 0; ch < 2; ++ch)
#pragma unroll
        for (int r = 0; r < 16; ++r)
          S[((qs * 2 + ch) * 16 + r) * 64 + l] = O[qs][ch][r];
      LSs[(w - 2) * 128 + qs * 64 + l] = ls[qs];
    }
  }
  __syncthreads();
  if (w < 2) {
    const float* S = MS + w * 4096;
#pragma unroll
    for (int qs = 0; qs < 2; ++qs) {
#pragma unroll
      for (int ch = 0; ch < 2; ++ch)
#pragma unroll
        for (int r = 0; r < 16; ++r)
          O[qs][ch][r] += S[((qs * 2 + ch) * 16 + r) * 64 + l];
      ls[qs] += LSs[w * 128 + qs * 64 + l];
    }
  }
  __syncthreads();
  if (w == 1) {
    float* S = MS;
#pragma unroll
    for (int qs = 0; qs < 2; ++qs) {
#pragma unroll
      for (int ch = 0; ch < 2; ++ch)
#pragma unroll
        for (int r = 0; r < 16; ++r)
          S[((qs * 2 + ch) * 16 + r) * 64 + l] = O[qs][ch][r];
      LSs[qs * 64 + l] = ls[qs];
    }
  }
  __syncthreads();
  bf16* HT = (bf16*)(MS + 2 * 4096);  // slot2 region (dead): h' [64 q][72 c]
  if (w == 0) {
    const float* S = MS;
#pragma unroll
    for (int qs = 0; qs < 2; ++qs) {
#pragma unroll
      for (int ch = 0; ch < 2; ++ch)
#pragma unroll
        for (int r = 0; r < 16; ++r)
          O[qs][ch][r] += S[((qs * 2 + ch) * 16 + r) * 64 + l];
      ls[qs] += LSs[qs * 64 + l];
      const float lv = 1.0f / ls[qs];
      const int qrow = qs * 32 + q31;
#pragma unroll
      for (int ch = 0; ch < 2; ++ch)
#pragma unroll
        for (int g = 0; g < 4; ++g) {
          union { ushort4 u; short s[4]; } pk_;
#pragma unroll
          for (int rr = 0; rr < 4; ++rr)
            pk_.s[rr] = f2bs(O[qs][ch][g * 4 + rr] * lv);
          // c = ch*32 + (r&3) + 8*(r>>2) + 4*hi
          *(ushort4*)&HT[qrow * 72 + ch * 32 + g * 8 + hi * 4] = pk_.u;
        }
    }
  }
  __syncthreads();
  // proj: out[o,n] = wp[o,:] . h'[:,n] + bp[o] + x[o,n]; 8 waves: (jb o) x (qh n)
  const int li = l & 15, quad = l >> 4;
  const int jb = w & 3, qh = w >> 2;
  short8 Wa[2];
#pragma unroll
  for (int ks = 0; ks < 2; ++ks)
    Wa[ks] = ld8<F32>(wp, (jb * 16 + li) * 64 + ks * 32 + quad * 8);
  float bpv[4];
#pragma unroll
  for (int r = 0; r < 4; ++r) bpv[r] = ldx<F32>(bp, jb * 16 + quad * 4 + r);
#pragma unroll
  for (int nb = 0; nb < 2; ++nb) {
    short8 Hf[2];
#pragma unroll
    for (int ks = 0; ks < 2; ++ks)
      Hf[ks] = *(const short8*)&HT[(qh * 32 + nb * 16 + li) * 72 + ks * 32 + quad * 8];
    f32x4 acc = {0.f, 0.f, 0.f, 0.f};
    acc = mfma32(Wa[0], Hf[0], acc);
    acc = mfma32(Wa[1], Hf[1], acc);
#pragma unroll
    for (int r = 0; r < 4; ++r) {
      const int o = jb * 16 + quad * 4 + r;
      const int n = qt * 64 + qh * 32 + nb * 16 + li;
      const size_t idx = ((size_t)(b * 64 + o)) * N_ + n;
      const float res = ldx<F32>(xg, idx) + acc[r] + bpv[r];
      if (F32) ((float*)outv)[idx] = res;
      else ((bf16*)outv)[idx] = __float2bfloat16(res);
    }
  }
}

__global__ __launch_bounds__(512, 2) void k_attnproj(
    const bf16* __restrict__ qg, const bf16* __restrict__ kg,
    const bf16* __restrict__ vg, const void* __restrict__ xg,
    const void* __restrict__ wp, const void* __restrict__ bp,
    const int* __restrict__ flag, void* __restrict__ outv) {
  __shared__ float MS[4 * 4096];   // 64 KB merge slots (slot2 reused as HT)
  __shared__ float LSs[4 * 128];   // 2 KB ls slots
  const int bid = blockIdx.x;
  const int x = bid & 7;            // XCD: each XCD pair serves one batch
  const int b = x >> 1, qt = (bid >> 3) * 2 + (x & 1);
  if (*flag)
    attnproj_body<true>(qg, kg, vg, xg, wp, bp, outv, MS, LSs, b, qt);
  else
    attnproj_body<false>(qg, kg, vg, xg, wp, bp, outv, MS, LSs, b, qt);
}

// ---------------- launcher --------------------------------------------------
extern "C" void kernel_launch(void* const* d_in, const int* in_sizes, int n_in,
                              void* d_out, int out_size, void* d_ws,
                              size_t ws_size, hipStream_t stream) {
  const void* x = d_in[0];
  const void* wqkv = d_in[1];
  const void* bqkv = d_in[2];
  const void* wproj = d_in[3];
  const void* bproj = d_in[4];

  char* ws = (char*)d_ws;
  float* meanArr = (float*)ws;                      // 1 KB
  float* rstdArr = (float*)(ws + 1024);             // 1 KB
  int* flag = (int*)(ws + 2048);
  bf16* q = (bf16*)(ws + 4096);                     // 2 MB
  bf16* k = (bf16*)(ws + 4096 + (2u << 20));        // 2 MB
  bf16* v = (bf16*)(ws + 4096 + (4u << 20));        // 2 MB

  k_stats<<<256, 256, 0, stream>>>(x, meanArr, rstdArr, flag);
  k_qkv<<<dim3(64, 4), 256, 0, stream>>>(x, wqkv, bqkv, meanArr, rstdArr, q, k,
                                         v, flag);
  k_attnproj<<<256, 512, 0, stream>>>(q, k, v, x, wproj, bproj, flag, d_out);
}